// Round 6
// baseline (777.001 us; speedup 1.0000x reference)
//
#include <hip/hip_runtime.h>

#define EPSN 1e-12f

using frag_ab = __attribute__((ext_vector_type(8))) short;   // 8 bf16
using frag_cd = __attribute__((ext_vector_type(4))) float;   // 4 fp32

__device__ inline unsigned short f2bf(float x) {
    union { float f; unsigned u; } v; v.f = x;
    unsigned r = v.u + 0x7fffu + ((v.u >> 16) & 1u);   // round-to-nearest-even
    return (unsigned short)(r >> 16);
}
__device__ inline float bf2f(unsigned short b) {
    union { unsigned u; float f; } v; v.u = ((unsigned)b) << 16; return v.f;
}

// ---------------- pre: h0 = relu(x @ pre_w + pre_b) -> bf16 [N,32] ------------
__global__ void pre_linear(const float* __restrict__ x, const float* __restrict__ w,
                           const float* __restrict__ b, unsigned short* __restrict__ h0,
                           int n) {
    int idx = blockIdx.x * blockDim.x + threadIdx.x;
    if (idx >= n * 32) return;
    int node = idx >> 5, j = idx & 31;
    float v = b[j];
#pragma unroll
    for (int k = 0; k < 5; ++k) v += x[node * 5 + k] * w[k * 32 + j];
    h0[idx] = f2bf(fmaxf(v, 0.f));
}

// ---------------- partition build (64 nodes per partition) --------------------
// phist: count edges per partition (dst>>6). NP ~1563 counters -> L2-resident.
__global__ void phist_k(const int* __restrict__ dst, int* __restrict__ pcnt, int e) {
    int i = blockIdx.x * blockDim.x + threadIdx.x;
    if (i < e) atomicAdd(&pcnt[dst[i] >> 6], 1);
}

// single-wave exclusive scan over NP partition counts; writes poffs and pcur
__global__ void pscan_k(const int* __restrict__ pcnt, int* __restrict__ poffs,
                        int* __restrict__ pcur, int np, int e) {
    int lane = threadIdx.x;  // 64 threads
    int run = 0;
    for (int base = 0; base < np; base += 64) {
        int i = base + lane;
        int x = (i < np) ? pcnt[i] : 0;
        int inc = x;
#pragma unroll
        for (int o = 1; o < 64; o <<= 1) {
            int t = __shfl_up(inc, o);
            if (lane >= o) inc += t;
        }
        if (i < np) {
            int v = inc - x + run;
            poffs[i] = v;
            pcur[i] = v;
        }
        run += __shfl(inc, 63);
    }
    if (lane == 0) poffs[np] = e;
}

// scatter packed (src<<6 | dst&63) into partition slots. Active-line set =
// NP*64B ~ 100 KB -> lines fill completely in L2 before eviction (round-5
// fill_k wrote 105 MB of partial lines for a 6.4 MB array; this writes ~6.4 MB).
__global__ void part_k(const int* __restrict__ src, const int* __restrict__ dst,
                       int* __restrict__ pcur, int* __restrict__ pk, int e) {
    int i = blockIdx.x * blockDim.x + threadIdx.x;
    if (i < e) {
        int d = dst[i];
        int p = atomicAdd(&pcur[d >> 6], 1);
        pk[p] = (src[i] << 6) | (d & 63);
    }
}

// ---------------- SAGE conv via MFMA, fused per-block counting sort -----------
// Block = 256 thr (4 waves) = 64 nodes = one partition. The block LDS-sorts its
// ~1024 packed entries by dst&63 (histogram + wave scan + LDS scatter), which
// also yields per-node degrees. Gather: 16B/lane uint4 row loads (LPE=KIN/8
// lanes/edge, EPW=64/LPE edges/wave-load), shfl_xor cross-edge reduce,
// [agg|self] bf16 rows to LDS. Wave w then runs mfma_f32_16x16x32_bf16 for
// j-tile w over 4 M-tiles with weights in VGPR B-fragments. Epilogue: bias,
// cross-wave L2 norm, relu, store.
template <int KIN, bool OUTBF16>
__global__ __launch_bounds__(256) void conv_mfma(
    const int* __restrict__ poffs, const int* __restrict__ pk,
    const unsigned short* __restrict__ hin, const float* __restrict__ wl,
    const float* __restrict__ bl, const float* __restrict__ wr,
    void* __restrict__ hout, int n) {
    constexpr int KT = 2 * KIN;    // concat [agg|self]
    constexpr int ST = KT + 8;     // LDS row stride in ushorts (16B-aligned rows)
    constexpr int KS = KT / 32;    // MFMA k-steps
    constexpr int LPE = KIN / 8;   // lanes per edge row (16B each)
    constexpr int EPW = 64 / LPE;  // edges per wave-load
    constexpr int SCAP = 2048;     // partition cap (mean 1024, sigma 32)
    __shared__ unsigned short __attribute__((aligned(16))) Ab[64 * ST];
    __shared__ float __attribute__((aligned(16))) Nb[4 * 64];
    __shared__ int ssorted[SCAP];
    __shared__ int hcnt[64], hoff[64], hcur[64];

    int tid = threadIdx.x;
    int w = tid >> 6;              // wave id == j-tile
    int lane = tid & 63;
    int quad = lane >> 4;
    int l16 = lane & 15;
    int base = blockIdx.x * 64;

    // B fragments: B[k][n], n = lane&15 (col within tile), k = quad*8 + i
    frag_ab bfrag[KS];
    int ncol = w * 16 + l16;
#pragma unroll
    for (int s = 0; s < KS; ++s) {
        frag_ab f;
#pragma unroll
        for (int i = 0; i < 8; ++i) {
            int k = s * 32 + quad * 8 + i;
            float wv = (k < KIN) ? wl[k * 64 + ncol] : wr[(k - KIN) * 64 + ncol];
            f[i] = (short)f2bf(wv);
        }
        bfrag[s] = f;
    }
    float bias = bl[ncol];

    // ---- per-block counting sort of this partition's edges ----
    int pbeg = poffs[blockIdx.x];
    int pc = poffs[blockIdx.x + 1] - pbeg;
    if (pc > SCAP) pc = SCAP;
    if (tid < 64) hcnt[tid] = 0;
    __syncthreads();
    for (int i = tid; i < pc; i += 256) atomicAdd(&hcnt[pk[pbeg + i] & 63], 1);
    __syncthreads();
    if (tid < 64) {
        int x = hcnt[tid];
        int inc = x;
#pragma unroll
        for (int o = 1; o < 64; o <<= 1) {
            int t = __shfl_up(inc, o);
            if (lane >= o) inc += t;
        }
        hoff[tid] = inc - x;
        hcur[tid] = inc - x;
    }
    __syncthreads();
    for (int i = tid; i < pc; i += 256) {
        int v = pk[pbeg + i];
        int p = atomicAdd(&hcur[v & 63], 1);
        ssorted[p] = v >> 6;
    }
    __syncthreads();

    // ---- gather phase: wave w fills LDS rows w*16 .. w*16+15 ----
    int grp = lane / LPE;          // edge slot within a wave-load
    int p = lane % LPE;            // 16B chunk within a row
    for (int i = 0; i < 16; ++i) {
        int li = w * 16 + i;
        int node = base + li;
        if (node >= n) break;
        int beg = hoff[li], cnt = hcnt[li];
        uint4 selfv = make_uint4(0u, 0u, 0u, 0u);
        if (grp == 1)
            selfv = *(const uint4*)&hin[(size_t)node * KIN + p * 8];
        float a0 = 0.f, a1 = 0.f, a2 = 0.f, a3 = 0.f;
        float a4 = 0.f, a5 = 0.f, a6 = 0.f, a7 = 0.f;
#pragma unroll 2
        for (int e = 0; e < cnt; e += EPW) {
            int ee = e + grp;
            bool ok = (ee < cnt);
            int s = ssorted[beg + (ok ? ee : 0)];
            uint4 u = *(const uint4*)&hin[(size_t)s * KIN + p * 8];
            if (ok) {
                a0 += bf2f((unsigned short)u.x); a1 += bf2f((unsigned short)(u.x >> 16));
                a2 += bf2f((unsigned short)u.y); a3 += bf2f((unsigned short)(u.y >> 16));
                a4 += bf2f((unsigned short)u.z); a5 += bf2f((unsigned short)(u.z >> 16));
                a6 += bf2f((unsigned short)u.w); a7 += bf2f((unsigned short)(u.w >> 16));
            }
        }
        float acc[8] = {a0, a1, a2, a3, a4, a5, a6, a7};
#pragma unroll
        for (int o = LPE; o < 64; o <<= 1) {
#pragma unroll
            for (int q = 0; q < 8; ++q) acc[q] += __shfl_xor(acc[q], o);
        }
        float inv = (cnt > 0) ? 1.0f / (float)cnt : 0.0f;
        if (grp == 0) {
            uint4 o4;
            o4.x = (unsigned)f2bf(acc[0] * inv) | ((unsigned)f2bf(acc[1] * inv) << 16);
            o4.y = (unsigned)f2bf(acc[2] * inv) | ((unsigned)f2bf(acc[3] * inv) << 16);
            o4.z = (unsigned)f2bf(acc[4] * inv) | ((unsigned)f2bf(acc[5] * inv) << 16);
            o4.w = (unsigned)f2bf(acc[6] * inv) | ((unsigned)f2bf(acc[7] * inv) << 16);
            *(uint4*)&Ab[li * ST + p * 8] = o4;
        } else if (grp == 1) {
            *(uint4*)&Ab[li * ST + KIN + p * 8] = selfv;
        }
    }
    __syncthreads();

    // ---- MFMA phase: wave w computes cols [w*16, w*16+16) for 4 M-tiles ----
    frag_cd acc[4];
#pragma unroll
    for (int t = 0; t < 4; ++t) acc[t] = (frag_cd){0.f, 0.f, 0.f, 0.f};
#pragma unroll
    for (int t = 0; t < 4; ++t) {
#pragma unroll
        for (int s = 0; s < KS; ++s) {
            frag_ab af = *(frag_ab*)&Ab[(t * 16 + l16) * ST + s * 32 + quad * 8];
            acc[t] = __builtin_amdgcn_mfma_f32_16x16x32_bf16(af, bfrag[s], acc[t], 0, 0, 0);
        }
    }

    // ---- epilogue: bias, sumsq partials per node ----
    float vv[4][4];
#pragma unroll
    for (int t = 0; t < 4; ++t) {
        float q[4];
#pragma unroll
        for (int i = 0; i < 4; ++i) {
            float v = acc[t][i] + bias;   // D row = quad*4+i (node), col = l16
            vv[t][i] = v;
            q[i] = v * v;
        }
#pragma unroll
        for (int o = 1; o < 16; o <<= 1) {
#pragma unroll
            for (int i = 0; i < 4; ++i) q[i] += __shfl_xor(q[i], o);
        }
        if (l16 == 0) {
            float4 qq = make_float4(q[0], q[1], q[2], q[3]);
            *(float4*)&Nb[w * 64 + t * 16 + quad * 4] = qq;
        }
    }
    __syncthreads();

#pragma unroll
    for (int t = 0; t < 4; ++t) {
        float s0 = 0.f, s1 = 0.f, s2 = 0.f, s3 = 0.f;
#pragma unroll
        for (int ww = 0; ww < 4; ++ww) {
            float4 xq = *(const float4*)&Nb[ww * 64 + t * 16 + quad * 4];
            s0 += xq.x; s1 += xq.y; s2 += xq.z; s3 += xq.w;
        }
        float ss[4] = {s0, s1, s2, s3};
#pragma unroll
        for (int i = 0; i < 4; ++i) {
            int node = base + t * 16 + quad * 4 + i;
            if (node < n) {
                float nv = fmaxf(sqrtf(ss[i]), EPSN);
                float outv = fmaxf(vv[t][i] / nv, 0.f);
                if (OUTBF16)
                    ((unsigned short*)hout)[(size_t)node * 64 + ncol] = f2bf(outv);
                else
                    ((float*)hout)[(size_t)node * 64 + ncol] = outv;
            }
        }
    }
}

// ---------------- fused pool (batch sorted) + head MLP ------------------------
__global__ __launch_bounds__(256) void pool_mlp_k(
    const float* __restrict__ h, const int* __restrict__ batch, int n,
    const float* __restrict__ p1w, const float* __restrict__ p1b,
    const float* __restrict__ p2w, const float* __restrict__ p2b,
    const float* __restrict__ ow, const float* __restrict__ ob,
    float* __restrict__ out) {
    __shared__ float part[4][64];
    __shared__ float gmean[64];
    __shared__ float a1[64];
    __shared__ float a2[16];
    int g = blockIdx.x;
    int w = threadIdx.x >> 6, j = threadIdx.x & 63;
    int lo = 0, hi = n;
    while (lo < hi) { int m = (lo + hi) >> 1; if (batch[m] < g) lo = m + 1; else hi = m; }
    int start = lo;
    hi = n;
    while (lo < hi) { int m = (lo + hi) >> 1; if (batch[m] < g + 1) lo = m + 1; else hi = m; }
    int end = lo;
    float acc = 0.f;
    for (int node = start + w; node < end; node += 4)
        acc += h[(size_t)node * 64 + j];
    part[w][j] = acc;
    __syncthreads();
    if (w == 0) {
        float s = part[0][j] + part[1][j] + part[2][j] + part[3][j];
        float c = (float)(end - start);
        gmean[j] = s / fmaxf(c, 1.0f);
    }
    __syncthreads();
    if (w == 0) {
        float v = p1b[j];
#pragma unroll 8
        for (int k = 0; k < 64; ++k) v = fmaf(gmean[k], p1w[k * 64 + j], v);
        a1[j] = fmaxf(v, 0.f);
    }
    __syncthreads();
    if (w == 0 && j < 16) {
        float v2 = p2b[j];
#pragma unroll 8
        for (int k = 0; k < 64; ++k) v2 = fmaf(a1[k], p2w[k * 16 + j], v2);
        a2[j] = fmaxf(v2, 0.f);
    }
    __syncthreads();
    if (threadIdx.x == 0) {
        float v3 = ob[0];
#pragma unroll
        for (int k = 0; k < 16; ++k) v3 = fmaf(a2[k], ow[k], v3);
        out[g] = v3;
    }
}

extern "C" void kernel_launch(void* const* d_in, const int* in_sizes, int n_in,
                              void* d_out, int out_size, void* d_ws, size_t ws_size,
                              hipStream_t stream) {
    const float* x     = (const float*)d_in[0];
    const int*   ei    = (const int*)d_in[1];
    const int*   batch = (const int*)d_in[2];
    const float* pre_w = (const float*)d_in[4];
    const float* pre_b = (const float*)d_in[5];
    const float* c1_wl = (const float*)d_in[6];
    const float* c1_bl = (const float*)d_in[7];
    const float* c1_wr = (const float*)d_in[8];
    const float* c2_wl = (const float*)d_in[9];
    const float* c2_bl = (const float*)d_in[10];
    const float* c2_wr = (const float*)d_in[11];
    const float* p1w   = (const float*)d_in[12];
    const float* p1b   = (const float*)d_in[13];
    const float* p2w   = (const float*)d_in[14];
    const float* p2b   = (const float*)d_in[15];
    const float* ow    = (const float*)d_in[16];
    const float* ob    = (const float*)d_in[17];

    const int N = in_sizes[0] / 5;
    const int E = in_sizes[1] / 2;
    const int G = out_size;
    const int NP = (N + 63) / 64;   // partitions of 64 nodes
    const int* src = ei;
    const int* dst = ei + E;

    // workspace layout
    float* h2f = (float*)d_ws;                                      // N*64 f32
    unsigned short* h0u = (unsigned short*)(h2f + (size_t)N * 64);  // N*32 bf16
    unsigned short* h1u = h0u + (size_t)N * 32;                     // N*64 bf16
    int* pcnt  = (int*)(h1u + (size_t)N * 64);                      // NP
    int* poffs = pcnt + NP;                                         // NP+1
    int* pcur  = poffs + NP + 1;                                    // NP
    int* pk    = pcur + NP;                                         // E

    hipMemsetAsync(pcnt, 0, (size_t)NP * sizeof(int), stream);

    pre_linear<<<(N * 32 + 255) / 256, 256, 0, stream>>>(x, pre_w, pre_b, h0u, N);

    // partition build (shared by both convs)
    phist_k<<<(E + 255) / 256, 256, 0, stream>>>(dst, pcnt, E);
    pscan_k<<<1, 64, 0, stream>>>(pcnt, poffs, pcur, NP, E);
    part_k<<<(E + 255) / 256, 256, 0, stream>>>(src, dst, pcur, pk, E);

    conv_mfma<32, true><<<NP, 256, 0, stream>>>(poffs, pk, h0u, c1_wl, c1_bl, c1_wr,
                                                h1u, N);
    conv_mfma<64, false><<<NP, 256, 0, stream>>>(poffs, pk, h1u, c2_wl, c2_bl, c2_wr,
                                                 h2f, N);

    pool_mlp_k<<<G, 256, 0, stream>>>(h2f, batch, N, p1w, p1b, p2w, p2b, ow, ob,
                                      (float*)d_out);
}

// Round 7
// 464.201 us; speedup vs baseline: 1.6738x; 1.6738x over previous
//
#include <hip/hip_runtime.h>

#define EPSN 1e-12f
#define TILE 8192   // edges per pass-1 tile
#define SBN 512     // nodes per coarse bucket (key = dst>>9)

using frag_ab = __attribute__((ext_vector_type(8))) short;   // 8 bf16
using frag_cd = __attribute__((ext_vector_type(4))) float;   // 4 fp32

__device__ inline unsigned short f2bf(float x) {
    union { float f; unsigned u; } v; v.f = x;
    unsigned r = v.u + 0x7fffu + ((v.u >> 16) & 1u);   // round-to-nearest-even
    return (unsigned short)(r >> 16);
}
__device__ inline float bf2f(unsigned short b) {
    union { unsigned u; float f; } v; v.u = ((unsigned)b) << 16; return v.f;
}

// ---------------- pre: h0 = relu(x @ pre_w + pre_b) -> bf16 [N,32] ------------
__global__ void pre_linear(const float* __restrict__ x, const float* __restrict__ w,
                           const float* __restrict__ b, unsigned short* __restrict__ h0,
                           int n) {
    int idx = blockIdx.x * blockDim.x + threadIdx.x;
    if (idx >= n * 32) return;
    int node = idx >> 5, j = idx & 31;
    float v = b[j];
#pragma unroll
    for (int k = 0; k < 5; ++k) v += x[node * 5 + k] * w[k * 32 + j];
    h0[idx] = f2bf(fmaxf(v, 0.f));
}

// ---------------- degree histogram (100k counters: ~16-way contention, cheap) -
__global__ void hist_k(const int* __restrict__ dst, int* __restrict__ deg, int e) {
    int i = blockIdx.x * blockDim.x + threadIdx.x;
    if (i < e) atomicAdd(&deg[dst[i]], 1);
}

// ---------------- rofs = exclusive scan of deg --------------------------------
__global__ void scan_block_k(const int* __restrict__ deg, int* __restrict__ rofs,
                             int* __restrict__ partials, int n) {
    __shared__ int wsum[8];
    int i = blockIdx.x * 256 + threadIdx.x;
    int x = (i < n) ? deg[i] : 0;
    int lane = threadIdx.x & 63, w = threadIdx.x >> 6;
    int inc = x;
#pragma unroll
    for (int o = 1; o < 64; o <<= 1) {
        int t = __shfl_up(inc, o);
        if (lane >= o) inc += t;
    }
    if (lane == 63) wsum[w] = inc;
    __syncthreads();
    if (threadIdx.x == 0) {
        int s = 0;
#pragma unroll
        for (int k = 0; k < 4; ++k) { int t = wsum[k]; wsum[k] = s; s += t; }
        wsum[4] = s;
    }
    __syncthreads();
    if (i < n) rofs[i] = inc - x + wsum[w];
    if (threadIdx.x == 255) partials[blockIdx.x] = wsum[4];
}

__global__ void scan_partials_k(int* __restrict__ partials, int nb) {
    int lane = threadIdx.x;  // 64 threads
    int run = 0;
    for (int base = 0; base < nb; base += 64) {
        int i = base + lane;
        int x = (i < nb) ? partials[i] : 0;
        int inc = x;
#pragma unroll
        for (int o = 1; o < 64; o <<= 1) {
            int t = __shfl_up(inc, o);
            if (lane >= o) inc += t;
        }
        if (i < nb) partials[i] = inc - x + run;
        run += __shfl(inc, 63);
    }
}

__global__ void add_offs_k(int* __restrict__ rofs, const int* __restrict__ partials,
                           int n, int e) {
    int i = blockIdx.x * 256 + threadIdx.x;
    if (i < n) rofs[i] += partials[i >> 8];
    if (i == n) rofs[n] = e;
}

// ---------------- pass 1a: per-tile histogram over coarse buckets -------------
__global__ __launch_bounds__(256) void thist_k(const int* __restrict__ dst,
                                               int* __restrict__ thist, int e, int nsb) {
    __shared__ int lh[SBN];
    int tid = threadIdx.x;
    for (int i = tid; i < nsb; i += 256) lh[i] = 0;
    __syncthreads();
    int base = blockIdx.x * TILE;
    int lim = min(base + TILE, e);
    for (int i = base + tid; i < lim; i += 256) atomicAdd(&lh[dst[i] >> 9], 1);
    __syncthreads();
    for (int i = tid; i < nsb; i += 256) thist[blockIdx.x * nsb + i] = lh[i];
}

// ---------------- pass 1b: per-(tile,bucket) global offsets -------------------
// toffs[t][b] = rofs[bucket b start] + sum_{t'<t} thist[t'][b]
__global__ void toffs_k(const int* __restrict__ rofs, const int* __restrict__ thist,
                        int* __restrict__ toffs, int n, int nt, int nsb) {
    int b = blockIdx.x * blockDim.x + threadIdx.x;
    if (b >= nsb) return;
    int nlo = b << 9;
    if (nlo > n) nlo = n;
    int run = rofs[nlo];
    for (int t = 0; t < nt; ++t) {
        toffs[t * nsb + b] = run;
        run += thist[t * nsb + b];
    }
}

// ---------------- pass 1c: scatter into bucket-grouped staging ----------------
// Each [tile][bucket] destination range is private to this block and contiguous
// (~42 entries): single-writer lines, full-line evictions (round-6's part_k
// failed on cross-XCD shared lines + 1024-way atomic contention).
__global__ __launch_bounds__(256) void scat1_k(const int* __restrict__ src,
                                               const int* __restrict__ dst,
                                               const int* __restrict__ toffs,
                                               int* __restrict__ staged, int e, int nsb) {
    __shared__ int cur[SBN];
    int tid = threadIdx.x;
    for (int i = tid; i < nsb; i += 256) cur[i] = toffs[blockIdx.x * nsb + i];
    __syncthreads();
    int base = blockIdx.x * TILE;
    int lim = min(base + TILE, e);
    for (int i = base + tid; i < lim; i += 256) {
        int d = dst[i];
        int p = atomicAdd(&cur[d >> 9], 1);
        staged[p] = (src[i] << 9) | (d & 511);   // src < 2^23, fits
    }
}

// ---------------- pass 2: per-bucket LDS counting sort -> CSR-ordered csr -----
// One block per bucket; bucket's staged range holds ALL edges of its 512-node
// dst range, so local excl-scan positions == global rofs order. csr writes are
// a private contiguous ~32KB region per block (single-writer lines).
__global__ __launch_bounds__(256) void scat2_k(const int* __restrict__ rofs,
                                               const int* __restrict__ staged,
                                               int* __restrict__ csr, int n) {
    __shared__ int h[SBN];
    __shared__ int cur[SBN];
    __shared__ int wsum[8];
    int b = blockIdx.x;
    int tid = threadIdx.x;
    int lane = tid & 63, w = tid >> 6;
    int nlo = b << 9, nhi = (b + 1) << 9;
    if (nlo > n) nlo = n;
    if (nhi > n) nhi = n;
    int lo = rofs[nlo], hi = rofs[nhi];
    h[tid] = 0;
    h[tid + 256] = 0;
    __syncthreads();
    for (int i = lo + tid; i < hi; i += 256) atomicAdd(&h[staged[i] & 511], 1);
    __syncthreads();
    // exclusive scan of 512 counts with 256 threads (2 per thread)
    int a0 = h[2 * tid], a1 = h[2 * tid + 1];
    int ps = a0 + a1;
    int inc = ps;
#pragma unroll
    for (int o = 1; o < 64; o <<= 1) {
        int t = __shfl_up(inc, o);
        if (lane >= o) inc += t;
    }
    if (lane == 63) wsum[w] = inc;
    __syncthreads();
    if (tid == 0) {
        int s = 0;
#pragma unroll
        for (int k = 0; k < 4; ++k) { int t = wsum[k]; wsum[k] = s; s += t; }
    }
    __syncthreads();
    int excl = inc - ps + wsum[w];
    cur[2 * tid] = excl;
    cur[2 * tid + 1] = excl + a0;
    __syncthreads();
    for (int i = lo + tid; i < hi; i += 256) {
        int v = staged[i];
        int p = atomicAdd(&cur[v & 511], 1);
        csr[lo + p] = v >> 9;
    }
}

// ---------------- SAGE conv via MFMA (round-5 version) ------------------------
// Block = 256 thr (4 waves) = 64 nodes. Gather: 16B/lane uint4 row loads
// (LPE=KIN/8 lanes/edge, EPW=64/LPE edges/wave-load), shfl_xor cross-edge
// reduce, [agg|self] bf16 rows to LDS; wave w runs mfma_f32_16x16x32_bf16 for
// j-tile w over 4 M-tiles, weights in VGPR B-fragments. Epilogue: bias,
// cross-wave L2 norm, relu, store.
template <int KIN, bool OUTBF16>
__global__ __launch_bounds__(256) void conv_mfma(
    const int* __restrict__ rofs, const int* __restrict__ csr,
    const unsigned short* __restrict__ hin, const float* __restrict__ wl,
    const float* __restrict__ bl, const float* __restrict__ wr,
    void* __restrict__ hout, int n) {
    constexpr int KT = 2 * KIN;    // concat [agg|self]
    constexpr int ST = KT + 8;     // LDS row stride in ushorts (16B-aligned rows)
    constexpr int KS = KT / 32;    // MFMA k-steps
    constexpr int LPE = KIN / 8;   // lanes per edge row (16B each)
    constexpr int EPW = 64 / LPE;  // edges per wave-load
    __shared__ unsigned short __attribute__((aligned(16))) Ab[64 * ST];
    __shared__ float __attribute__((aligned(16))) Nb[4 * 64];

    int w = threadIdx.x >> 6;      // wave id == j-tile
    int lane = threadIdx.x & 63;
    int quad = lane >> 4;
    int l16 = lane & 15;
    int base = blockIdx.x * 64;

    // B fragments: B[k][n], n = lane&15 (col within tile), k = quad*8 + i
    frag_ab bfrag[KS];
    int ncol = w * 16 + l16;
#pragma unroll
    for (int s = 0; s < KS; ++s) {
        frag_ab f;
#pragma unroll
        for (int i = 0; i < 8; ++i) {
            int k = s * 32 + quad * 8 + i;
            float wv = (k < KIN) ? wl[k * 64 + ncol] : wr[(k - KIN) * 64 + ncol];
            f[i] = (short)f2bf(wv);
        }
        bfrag[s] = f;
    }
    float bias = bl[ncol];

    // ---- gather phase: wave w fills LDS rows w*16 .. w*16+15 ----
    int grp = lane / LPE;          // edge slot within a wave-load
    int p = lane % LPE;            // 16B chunk within a row
    for (int i = 0; i < 16; ++i) {
        int li = w * 16 + i;
        int node = base + li;
        if (node >= n) break;
        int beg = rofs[node], end = rofs[node + 1];
        int cnt = end - beg;
        uint4 selfv = make_uint4(0u, 0u, 0u, 0u);
        if (grp == 1)
            selfv = *(const uint4*)&hin[(size_t)node * KIN + p * 8];
        float a0 = 0.f, a1 = 0.f, a2 = 0.f, a3 = 0.f;
        float a4 = 0.f, a5 = 0.f, a6 = 0.f, a7 = 0.f;
#pragma unroll 2
        for (int e = 0; e < cnt; e += EPW) {
            int ee = e + grp;
            bool ok = (ee < cnt);
            int s = csr[beg + (ok ? ee : 0)];
            uint4 u = *(const uint4*)&hin[(size_t)s * KIN + p * 8];
            if (ok) {
                a0 += bf2f((unsigned short)u.x); a1 += bf2f((unsigned short)(u.x >> 16));
                a2 += bf2f((unsigned short)u.y); a3 += bf2f((unsigned short)(u.y >> 16));
                a4 += bf2f((unsigned short)u.z); a5 += bf2f((unsigned short)(u.z >> 16));
                a6 += bf2f((unsigned short)u.w); a7 += bf2f((unsigned short)(u.w >> 16));
            }
        }
        float acc[8] = {a0, a1, a2, a3, a4, a5, a6, a7};
#pragma unroll
        for (int o = LPE; o < 64; o <<= 1) {
#pragma unroll
            for (int q = 0; q < 8; ++q) acc[q] += __shfl_xor(acc[q], o);
        }
        float inv = (cnt > 0) ? 1.0f / (float)cnt : 0.0f;
        if (grp == 0) {
            uint4 o4;
            o4.x = (unsigned)f2bf(acc[0] * inv) | ((unsigned)f2bf(acc[1] * inv) << 16);
            o4.y = (unsigned)f2bf(acc[2] * inv) | ((unsigned)f2bf(acc[3] * inv) << 16);
            o4.z = (unsigned)f2bf(acc[4] * inv) | ((unsigned)f2bf(acc[5] * inv) << 16);
            o4.w = (unsigned)f2bf(acc[6] * inv) | ((unsigned)f2bf(acc[7] * inv) << 16);
            *(uint4*)&Ab[li * ST + p * 8] = o4;
        } else if (grp == 1) {
            *(uint4*)&Ab[li * ST + KIN + p * 8] = selfv;
        }
    }
    __syncthreads();

    // ---- MFMA phase: wave w computes cols [w*16, w*16+16) for 4 M-tiles ----
    frag_cd acc[4];
#pragma unroll
    for (int t = 0; t < 4; ++t) acc[t] = (frag_cd){0.f, 0.f, 0.f, 0.f};
#pragma unroll
    for (int t = 0; t < 4; ++t) {
#pragma unroll
        for (int s = 0; s < KS; ++s) {
            frag_ab af = *(frag_ab*)&Ab[(t * 16 + l16) * ST + s * 32 + quad * 8];
            acc[t] = __builtin_amdgcn_mfma_f32_16x16x32_bf16(af, bfrag[s], acc[t], 0, 0, 0);
        }
    }

    // ---- epilogue: bias, sumsq partials per node ----
    float vv[4][4];
#pragma unroll
    for (int t = 0; t < 4; ++t) {
        float q[4];
#pragma unroll
        for (int i = 0; i < 4; ++i) {
            float v = acc[t][i] + bias;   // D row = quad*4+i (node), col = l16
            vv[t][i] = v;
            q[i] = v * v;
        }
#pragma unroll
        for (int o = 1; o < 16; o <<= 1) {
#pragma unroll
            for (int i = 0; i < 4; ++i) q[i] += __shfl_xor(q[i], o);
        }
        if (l16 == 0) {
            float4 qq = make_float4(q[0], q[1], q[2], q[3]);
            *(float4*)&Nb[w * 64 + t * 16 + quad * 4] = qq;
        }
    }
    __syncthreads();

#pragma unroll
    for (int t = 0; t < 4; ++t) {
        float s0 = 0.f, s1 = 0.f, s2 = 0.f, s3 = 0.f;
#pragma unroll
        for (int ww = 0; ww < 4; ++ww) {
            float4 xq = *(const float4*)&Nb[ww * 64 + t * 16 + quad * 4];
            s0 += xq.x; s1 += xq.y; s2 += xq.z; s3 += xq.w;
        }
        float ss[4] = {s0, s1, s2, s3};
#pragma unroll
        for (int i = 0; i < 4; ++i) {
            int node = base + t * 16 + quad * 4 + i;
            if (node < n) {
                float nv = fmaxf(sqrtf(ss[i]), EPSN);
                float outv = fmaxf(vv[t][i] / nv, 0.f);
                if (OUTBF16)
                    ((unsigned short*)hout)[(size_t)node * 64 + ncol] = f2bf(outv);
                else
                    ((float*)hout)[(size_t)node * 64 + ncol] = outv;
            }
        }
    }
}

// ---------------- fused pool (batch sorted) + head MLP ------------------------
__global__ __launch_bounds__(256) void pool_mlp_k(
    const float* __restrict__ h, const int* __restrict__ batch, int n,
    const float* __restrict__ p1w, const float* __restrict__ p1b,
    const float* __restrict__ p2w, const float* __restrict__ p2b,
    const float* __restrict__ ow, const float* __restrict__ ob,
    float* __restrict__ out) {
    __shared__ float part[4][64];
    __shared__ float gmean[64];
    __shared__ float a1[64];
    __shared__ float a2[16];
    int g = blockIdx.x;
    int w = threadIdx.x >> 6, j = threadIdx.x & 63;
    int lo = 0, hi = n;
    while (lo < hi) { int m = (lo + hi) >> 1; if (batch[m] < g) lo = m + 1; else hi = m; }
    int start = lo;
    hi = n;
    while (lo < hi) { int m = (lo + hi) >> 1; if (batch[m] < g + 1) lo = m + 1; else hi = m; }
    int end = lo;
    float acc = 0.f;
    for (int node = start + w; node < end; node += 4)
        acc += h[(size_t)node * 64 + j];
    part[w][j] = acc;
    __syncthreads();
    if (w == 0) {
        float s = part[0][j] + part[1][j] + part[2][j] + part[3][j];
        float c = (float)(end - start);
        gmean[j] = s / fmaxf(c, 1.0f);
    }
    __syncthreads();
    if (w == 0) {
        float v = p1b[j];
#pragma unroll 8
        for (int k = 0; k < 64; ++k) v = fmaf(gmean[k], p1w[k * 64 + j], v);
        a1[j] = fmaxf(v, 0.f);
    }
    __syncthreads();
    if (w == 0 && j < 16) {
        float v2 = p2b[j];
#pragma unroll 8
        for (int k = 0; k < 64; ++k) v2 = fmaf(a1[k], p2w[k * 16 + j], v2);
        a2[j] = fmaxf(v2, 0.f);
    }
    __syncthreads();
    if (threadIdx.x == 0) {
        float v3 = ob[0];
#pragma unroll
        for (int k = 0; k < 16; ++k) v3 = fmaf(a2[k], ow[k], v3);
        out[g] = v3;
    }
}

extern "C" void kernel_launch(void* const* d_in, const int* in_sizes, int n_in,
                              void* d_out, int out_size, void* d_ws, size_t ws_size,
                              hipStream_t stream) {
    const float* x     = (const float*)d_in[0];
    const int*   ei    = (const int*)d_in[1];
    const int*   batch = (const int*)d_in[2];
    const float* pre_w = (const float*)d_in[4];
    const float* pre_b = (const float*)d_in[5];
    const float* c1_wl = (const float*)d_in[6];
    const float* c1_bl = (const float*)d_in[7];
    const float* c1_wr = (const float*)d_in[8];
    const float* c2_wl = (const float*)d_in[9];
    const float* c2_bl = (const float*)d_in[10];
    const float* c2_wr = (const float*)d_in[11];
    const float* p1w   = (const float*)d_in[12];
    const float* p1b   = (const float*)d_in[13];
    const float* p2w   = (const float*)d_in[14];
    const float* p2b   = (const float*)d_in[15];
    const float* ow    = (const float*)d_in[16];
    const float* ob    = (const float*)d_in[17];

    const int N = in_sizes[0] / 5;
    const int E = in_sizes[1] / 2;
    const int G = out_size;
    const int NB = (N + 255) / 256;       // scan blocks
    const int NT = (E + TILE - 1) / TILE; // pass-1 tiles
    const int NSB = (N + SBN - 1) / SBN;  // coarse buckets (<= 512)
    const int* src = ei;
    const int* dst = ei + E;

    // workspace layout
    float* h2f = (float*)d_ws;                                      // N*64 f32
    unsigned short* h0u = (unsigned short*)(h2f + (size_t)N * 64);  // N*32 bf16
    unsigned short* h1u = h0u + (size_t)N * 32;                     // N*64 bf16
    int* deg      = (int*)(h1u + (size_t)N * 64);                   // N
    int* rofs     = deg + N;                                        // N+1
    int* partials = rofs + N + 1;                                   // NB
    int* thist    = partials + NB;                                  // NT*NSB
    int* toffs    = thist + (size_t)NT * NSB;                       // NT*NSB
    int* staged   = toffs + (size_t)NT * NSB;                       // E
    int* csr      = staged + E;                                     // E

    hipMemsetAsync(deg, 0, (size_t)N * sizeof(int), stream);

    pre_linear<<<(N * 32 + 255) / 256, 256, 0, stream>>>(x, pre_w, pre_b, h0u, N);

    // rofs (global CSR offsets)
    hist_k<<<(E + 255) / 256, 256, 0, stream>>>(dst, deg, E);
    scan_block_k<<<NB, 256, 0, stream>>>(deg, rofs, partials, N);
    scan_partials_k<<<1, 64, 0, stream>>>(partials, NB);
    add_offs_k<<<(N + 256) / 256, 256, 0, stream>>>(rofs, partials, N, E);

    // two-level bucket sort -> csr in CSR order
    thist_k<<<NT, 256, 0, stream>>>(dst, thist, E, NSB);
    toffs_k<<<(NSB + 255) / 256, 256, 0, stream>>>(rofs, thist, toffs, N, NT, NSB);
    scat1_k<<<NT, 256, 0, stream>>>(src, dst, toffs, staged, E, NSB);
    scat2_k<<<NSB, 256, 0, stream>>>(rofs, staged, csr, N);

    conv_mfma<32, true><<<(N + 63) / 64, 256, 0, stream>>>(rofs, csr, h0u, c1_wl,
                                                           c1_bl, c1_wr, h1u, N);
    conv_mfma<64, false><<<(N + 63) / 64, 256, 0, stream>>>(rofs, csr, h1u, c2_wl,
                                                            c2_bl, c2_wr, h2f, N);

    pool_mlp_k<<<G, 256, 0, stream>>>(h2f, batch, N, p1w, p1b, p2w, p2b, ow, ob,
                                      (float*)d_out);
}

// Round 8
// 373.325 us; speedup vs baseline: 2.0813x; 1.2434x over previous
//
#include <hip/hip_runtime.h>

#define EPSN 1e-12f
#define TILE 8192   // edges per pass-1 tile
#define SBN 512     // nodes per coarse bucket (key = dst>>9)

using frag_ab = __attribute__((ext_vector_type(8))) short;   // 8 bf16
using frag_cd = __attribute__((ext_vector_type(4))) float;   // 4 fp32

__device__ inline unsigned short f2bf(float x) {
    union { float f; unsigned u; } v; v.f = x;
    unsigned r = v.u + 0x7fffu + ((v.u >> 16) & 1u);   // round-to-nearest-even
    return (unsigned short)(r >> 16);
}
__device__ inline float bf2f(unsigned short b) {
    union { unsigned u; float f; } v; v.u = ((unsigned)b) << 16; return v.f;
}

// ---------------- pre: h0 = relu(x @ pre_w + pre_b) -> bf16 [N,32] ------------
__global__ void pre_linear(const float* __restrict__ x, const float* __restrict__ w,
                           const float* __restrict__ b, unsigned short* __restrict__ h0,
                           int n) {
    int idx = blockIdx.x * blockDim.x + threadIdx.x;
    if (idx >= n * 32) return;
    int node = idx >> 5, j = idx & 31;
    float v = b[j];
#pragma unroll
    for (int k = 0; k < 5; ++k) v += x[node * 5 + k] * w[k * 32 + j];
    h0[idx] = f2bf(fmaxf(v, 0.f));
}

// ---------------- weight pack: [j][s][quad][i] bf16 so a B-fragment is one ----
// 16B vector load. wpk[o] with o=(((j*KS)+s)*4+q)*8+i holds Wcat[s*32+q*8+i][j],
// Wcat = [wl ; wr] (KT = 2*kin rows).
__global__ void wprep_k(const float* __restrict__ wl, const float* __restrict__ wr,
                        unsigned short* __restrict__ wpk, int kin) {
    int kt = 2 * kin;
    int total = 64 * kt;
    int o = blockIdx.x * blockDim.x + threadIdx.x;
    if (o >= total) return;
    int ks32 = kt;                 // ks*32 == kt
    int j = o / ks32;
    int r = o % ks32;              // r = s*32 + q*8 + i == k
    int k = r;
    float v = (k < kin) ? wl[k * 64 + j] : wr[(k - kin) * 64 + j];
    wpk[o] = f2bf(v);
}

// ---------------- pass 1a: per-tile histogram over coarse buckets -------------
__global__ __launch_bounds__(256) void thist_k(const int* __restrict__ dst,
                                               int* __restrict__ thist, int e, int nsb) {
    __shared__ int lh[SBN];
    int tid = threadIdx.x;
    for (int i = tid; i < nsb; i += 256) lh[i] = 0;
    __syncthreads();
    int base = blockIdx.x * TILE;
    int lim = min(base + TILE, e);
    for (int i = base + tid; i < lim; i += 256) atomicAdd(&lh[dst[i] >> 9], 1);
    __syncthreads();
    for (int i = tid; i < nsb; i += 256) thist[blockIdx.x * nsb + i] = lh[i];
}

// ---------------- pass 1b: bucket bases + per-(tile,bucket) offsets -----------
// Single block; nsb <= 256. Replaces the N-length hist+scan chain entirely.
__global__ __launch_bounds__(256) void toffs2_k(const int* __restrict__ thist,
                                                int* __restrict__ toffs,
                                                int* __restrict__ bbase,
                                                int nt, int nsb, int e) {
    __shared__ int wsum[8];
    int tid = threadIdx.x;
    int lane = tid & 63, w = tid >> 6;
    int tot = 0;
    if (tid < nsb)
        for (int t = 0; t < nt; ++t) tot += thist[t * nsb + tid];
    int inc = tot;
#pragma unroll
    for (int o = 1; o < 64; o <<= 1) {
        int t = __shfl_up(inc, o);
        if (lane >= o) inc += t;
    }
    if (lane == 63) wsum[w] = inc;
    __syncthreads();
    if (tid == 0) {
        int s = 0;
#pragma unroll
        for (int k = 0; k < 4; ++k) { int t = wsum[k]; wsum[k] = s; s += t; }
    }
    __syncthreads();
    int excl = inc - tot + wsum[w];
    if (tid < nsb) bbase[tid] = excl;
    if (tid == 0) bbase[nsb] = e;
    if (tid < nsb) {
        int run = excl;
        for (int t = 0; t < nt; ++t) {
            toffs[t * nsb + tid] = run;
            run += thist[t * nsb + tid];
        }
    }
}

// ---------------- pass 1c: scatter into bucket-grouped staging ----------------
// Each [tile][bucket] range is block-private & contiguous: single-writer lines.
__global__ __launch_bounds__(256) void scat1_k(const int* __restrict__ src,
                                               const int* __restrict__ dst,
                                               const int* __restrict__ toffs,
                                               int* __restrict__ staged, int e, int nsb) {
    __shared__ int cur[SBN];
    int tid = threadIdx.x;
    for (int i = tid; i < nsb; i += 256) cur[i] = toffs[blockIdx.x * nsb + i];
    __syncthreads();
    int base = blockIdx.x * TILE;
    int lim = min(base + TILE, e);
    for (int i = base + tid; i < lim; i += 256) {
        int d = dst[i];
        int p = atomicAdd(&cur[d >> 9], 1);
        staged[p] = (src[i] << 9) | (d & 511);   // src < 2^23, fits
    }
}

// ---------------- pass 2: per-bucket sort -> csr (CSR order) + rofs -----------
// One block per bucket. The local 512-node histogram scan gives rofs for free
// (rofs[node] = bucket base + local exclusive scan) — the old N-length
// hist+scan chain is gone.
__global__ __launch_bounds__(256) void scat2_k(const int* __restrict__ bbase,
                                               const int* __restrict__ staged,
                                               int* __restrict__ csr,
                                               int* __restrict__ rofs,
                                               int n, int e, int nsb) {
    __shared__ int h[SBN];
    __shared__ int cur[SBN];
    __shared__ int wsum[8];
    int b = blockIdx.x;
    int tid = threadIdx.x;
    int lane = tid & 63, w = tid >> 6;
    int nlo = b << 9;
    int nn = n - nlo; if (nn > SBN) nn = SBN;   // live nodes in bucket
    int lo = bbase[b], hi = bbase[b + 1];
    h[tid] = 0;
    h[tid + 256] = 0;
    __syncthreads();
    for (int i = lo + tid; i < hi; i += 256) atomicAdd(&h[staged[i] & 511], 1);
    __syncthreads();
    int a0 = h[2 * tid], a1 = h[2 * tid + 1];
    int ps = a0 + a1;
    int inc = ps;
#pragma unroll
    for (int o = 1; o < 64; o <<= 1) {
        int t = __shfl_up(inc, o);
        if (lane >= o) inc += t;
    }
    if (lane == 63) wsum[w] = inc;
    __syncthreads();
    if (tid == 0) {
        int s = 0;
#pragma unroll
        for (int k = 0; k < 4; ++k) { int t = wsum[k]; wsum[k] = s; s += t; }
    }
    __syncthreads();
    int excl = inc - ps + wsum[w];
    cur[2 * tid] = excl;
    cur[2 * tid + 1] = excl + a0;
    __syncthreads();
    if (2 * tid < nn) rofs[nlo + 2 * tid] = lo + cur[2 * tid];
    if (2 * tid + 1 < nn) rofs[nlo + 2 * tid + 1] = lo + cur[2 * tid + 1];
    if (b == nsb - 1 && tid == 0) rofs[n] = e;
    __syncthreads();   // rofs must read cur before scatter mutates it
    for (int i = lo + tid; i < hi; i += 256) {
        int v = staged[i];
        int p = atomicAdd(&cur[v & 511], 1);
        csr[lo + p] = v >> 9;
    }
}

// ---------------- SAGE conv via MFMA, 32 nodes/block --------------------------
// Round-7 was grid-limited (1563 blocks -> 34% occupancy). Now 32 nodes/block
// (grid ~3125, 8 resident blocks/CU): wave w owns j-tile w (B-frags = KS 16B
// vector loads from packed wpk), gathers 8 nodes (16B/lane uint4 rows, shfl
// cross-edge reduce), then 2 M-tiles of mfma_f32_16x16x32_bf16. Epilogue:
// bias, cross-wave L2 norm via LDS, relu, store.
template <int KIN, bool OUTBF16>
__global__ __launch_bounds__(256) void conv_mfma(
    const int* __restrict__ rofs, const int* __restrict__ csr,
    const unsigned short* __restrict__ hin, const unsigned short* __restrict__ wpk,
    const float* __restrict__ bl, void* __restrict__ hout, int n) {
    constexpr int KT = 2 * KIN;    // concat [agg|self]
    constexpr int ST = KT + 8;     // LDS row stride in ushorts (16B-aligned rows)
    constexpr int KS = KT / 32;    // MFMA k-steps
    constexpr int LPE = KIN / 8;   // lanes per edge row (16B each)
    constexpr int EPW = 64 / LPE;  // edges per wave-load
    __shared__ unsigned short __attribute__((aligned(16))) Ab[32 * ST];
    __shared__ float __attribute__((aligned(16))) Nb[4][32];

    int w = threadIdx.x >> 6;      // wave id == j-tile
    int lane = threadIdx.x & 63;
    int quad = lane >> 4;
    int l16 = lane & 15;
    int base = blockIdx.x * 32;
    int ncol = w * 16 + l16;

    // B fragments: one 16B load each from packed weights
    frag_ab bfrag[KS];
#pragma unroll
    for (int s = 0; s < KS; ++s)
        bfrag[s] = *(const frag_ab*)&wpk[(((ncol * KS) + s) * 4 + quad) * 8];
    float bias = bl[ncol];

    // ---- gather phase: wave w fills LDS rows w*8 .. w*8+7 ----
    int grp = lane / LPE;          // edge slot within a wave-load
    int p = lane % LPE;            // 16B chunk within a row
    for (int i = 0; i < 8; ++i) {
        int li = w * 8 + i;
        int node = base + li;
        if (node >= n) break;
        int beg = rofs[node], end = rofs[node + 1];
        int cnt = end - beg;
        uint4 selfv = make_uint4(0u, 0u, 0u, 0u);
        if (grp == 1)
            selfv = *(const uint4*)&hin[(size_t)node * KIN + p * 8];
        float a0 = 0.f, a1 = 0.f, a2 = 0.f, a3 = 0.f;
        float a4 = 0.f, a5 = 0.f, a6 = 0.f, a7 = 0.f;
#pragma unroll 2
        for (int e = 0; e < cnt; e += EPW) {
            int ee = e + grp;
            bool ok = (ee < cnt);
            int s = csr[beg + (ok ? ee : 0)];
            uint4 u = *(const uint4*)&hin[(size_t)s * KIN + p * 8];
            if (ok) {
                a0 += bf2f((unsigned short)u.x); a1 += bf2f((unsigned short)(u.x >> 16));
                a2 += bf2f((unsigned short)u.y); a3 += bf2f((unsigned short)(u.y >> 16));
                a4 += bf2f((unsigned short)u.z); a5 += bf2f((unsigned short)(u.z >> 16));
                a6 += bf2f((unsigned short)u.w); a7 += bf2f((unsigned short)(u.w >> 16));
            }
        }
        float acc[8] = {a0, a1, a2, a3, a4, a5, a6, a7};
#pragma unroll
        for (int o = LPE; o < 64; o <<= 1) {
#pragma unroll
            for (int q = 0; q < 8; ++q) acc[q] += __shfl_xor(acc[q], o);
        }
        float inv = (cnt > 0) ? 1.0f / (float)cnt : 0.0f;
        if (grp == 0) {
            uint4 o4;
            o4.x = (unsigned)f2bf(acc[0] * inv) | ((unsigned)f2bf(acc[1] * inv) << 16);
            o4.y = (unsigned)f2bf(acc[2] * inv) | ((unsigned)f2bf(acc[3] * inv) << 16);
            o4.z = (unsigned)f2bf(acc[4] * inv) | ((unsigned)f2bf(acc[5] * inv) << 16);
            o4.w = (unsigned)f2bf(acc[6] * inv) | ((unsigned)f2bf(acc[7] * inv) << 16);
            *(uint4*)&Ab[li * ST + p * 8] = o4;
        } else if (grp == 1) {
            *(uint4*)&Ab[li * ST + KIN + p * 8] = selfv;
        }
    }
    __syncthreads();

    // ---- MFMA phase: wave w computes cols [w*16, w*16+16) for 2 M-tiles ----
    frag_cd acc[2];
#pragma unroll
    for (int t = 0; t < 2; ++t) acc[t] = (frag_cd){0.f, 0.f, 0.f, 0.f};
#pragma unroll
    for (int t = 0; t < 2; ++t) {
#pragma unroll
        for (int s = 0; s < KS; ++s) {
            frag_ab af = *(frag_ab*)&Ab[(t * 16 + l16) * ST + s * 32 + quad * 8];
            acc[t] = __builtin_amdgcn_mfma_f32_16x16x32_bf16(af, bfrag[s], acc[t], 0, 0, 0);
        }
    }

    // ---- epilogue: bias, per-node sumsq partials ----
    float vv[2][4];
#pragma unroll
    for (int t = 0; t < 2; ++t) {
        float q[4];
#pragma unroll
        for (int i = 0; i < 4; ++i) {
            float v = acc[t][i] + bias;   // D row = quad*4+i (node), col = l16
            vv[t][i] = v;
            q[i] = v * v;
        }
#pragma unroll
        for (int o = 1; o < 16; o <<= 1) {
#pragma unroll
            for (int i = 0; i < 4; ++i) q[i] += __shfl_xor(q[i], o);
        }
        if (l16 == 0) {
            float4 qq = make_float4(q[0], q[1], q[2], q[3]);
            *(float4*)&Nb[w][t * 16 + quad * 4] = qq;
        }
    }
    __syncthreads();

#pragma unroll
    for (int t = 0; t < 2; ++t) {
        float s0 = 0.f, s1 = 0.f, s2 = 0.f, s3 = 0.f;
#pragma unroll
        for (int ww = 0; ww < 4; ++ww) {
            float4 xq = *(const float4*)&Nb[ww][t * 16 + quad * 4];
            s0 += xq.x; s1 += xq.y; s2 += xq.z; s3 += xq.w;
        }
        float ss[4] = {s0, s1, s2, s3};
#pragma unroll
        for (int i = 0; i < 4; ++i) {
            int node = base + t * 16 + quad * 4 + i;
            if (node < n) {
                float nv = fmaxf(sqrtf(ss[i]), EPSN);
                float outv = fmaxf(vv[t][i] / nv, 0.f);
                if (OUTBF16)
                    ((unsigned short*)hout)[(size_t)node * 64 + ncol] = f2bf(outv);
                else
                    ((float*)hout)[(size_t)node * 64 + ncol] = outv;
            }
        }
    }
}

// ---------------- fused pool (batch sorted) + head MLP ------------------------
__global__ __launch_bounds__(256) void pool_mlp_k(
    const float* __restrict__ h, const int* __restrict__ batch, int n,
    const float* __restrict__ p1w, const float* __restrict__ p1b,
    const float* __restrict__ p2w, const float* __restrict__ p2b,
    const float* __restrict__ ow, const float* __restrict__ ob,
    float* __restrict__ out) {
    __shared__ float part[4][64];
    __shared__ float gmean[64];
    __shared__ float a1[64];
    __shared__ float a2[16];
    int g = blockIdx.x;
    int w = threadIdx.x >> 6, j = threadIdx.x & 63;
    int lo = 0, hi = n;
    while (lo < hi) { int m = (lo + hi) >> 1; if (batch[m] < g) lo = m + 1; else hi = m; }
    int start = lo;
    hi = n;
    while (lo < hi) { int m = (lo + hi) >> 1; if (batch[m] < g + 1) lo = m + 1; else hi = m; }
    int end = lo;
    float acc = 0.f;
    for (int node = start + w; node < end; node += 4)
        acc += h[(size_t)node * 64 + j];
    part[w][j] = acc;
    __syncthreads();
    if (w == 0) {
        float s = part[0][j] + part[1][j] + part[2][j] + part[3][j];
        float c = (float)(end - start);
        gmean[j] = s / fmaxf(c, 1.0f);
    }
    __syncthreads();
    if (w == 0) {
        float v = p1b[j];
#pragma unroll 8
        for (int k = 0; k < 64; ++k) v = fmaf(gmean[k], p1w[k * 64 + j], v);
        a1[j] = fmaxf(v, 0.f);
    }
    __syncthreads();
    if (w == 0 && j < 16) {
        float v2 = p2b[j];
#pragma unroll 8
        for (int k = 0; k < 64; ++k) v2 = fmaf(a1[k], p2w[k * 16 + j], v2);
        a2[j] = fmaxf(v2, 0.f);
    }
    __syncthreads();
    if (threadIdx.x == 0) {
        float v3 = ob[0];
#pragma unroll
        for (int k = 0; k < 16; ++k) v3 = fmaf(a2[k], ow[k], v3);
        out[g] = v3;
    }
}

extern "C" void kernel_launch(void* const* d_in, const int* in_sizes, int n_in,
                              void* d_out, int out_size, void* d_ws, size_t ws_size,
                              hipStream_t stream) {
    const float* x     = (const float*)d_in[0];
    const int*   ei    = (const int*)d_in[1];
    const int*   batch = (const int*)d_in[2];
    const float* pre_w = (const float*)d_in[4];
    const float* pre_b = (const float*)d_in[5];
    const float* c1_wl = (const float*)d_in[6];
    const float* c1_bl = (const float*)d_in[7];
    const float* c1_wr = (const float*)d_in[8];
    const float* c2_wl = (const float*)d_in[9];
    const float* c2_bl = (const float*)d_in[10];
    const float* c2_wr = (const float*)d_in[11];
    const float* p1w   = (const float*)d_in[12];
    const float* p1b   = (const float*)d_in[13];
    const float* p2w   = (const float*)d_in[14];
    const float* p2b   = (const float*)d_in[15];
    const float* ow    = (const float*)d_in[16];
    const float* ob    = (const float*)d_in[17];

    const int N = in_sizes[0] / 5;
    const int E = in_sizes[1] / 2;
    const int G = out_size;
    const int NT = (E + TILE - 1) / TILE; // pass-1 tiles
    const int NSB = (N + SBN - 1) / SBN;  // coarse buckets (<= 256)
    const int* src = ei;
    const int* dst = ei + E;

    // workspace layout
    float* h2f = (float*)d_ws;                                      // N*64 f32
    unsigned short* h0u = (unsigned short*)(h2f + (size_t)N * 64);  // N*32 bf16
    unsigned short* h1u = h0u + (size_t)N * 32;                     // N*64 bf16
    unsigned short* wpk1 = h1u + (size_t)N * 64;                    // 64*64
    unsigned short* wpk2 = wpk1 + 64 * 64;                          // 64*128
    int* rofs   = (int*)(wpk2 + 64 * 128);                          // N+1
    int* bbase  = rofs + N + 1;                                     // NSB+1
    int* thist  = bbase + NSB + 1;                                  // NT*NSB
    int* toffs  = thist + (size_t)NT * NSB;                         // NT*NSB
    int* staged = toffs + (size_t)NT * NSB;                         // E
    int* csr    = staged + E;                                       // E

    pre_linear<<<(N * 32 + 255) / 256, 256, 0, stream>>>(x, pre_w, pre_b, h0u, N);
    wprep_k<<<(64 * 64 + 255) / 256, 256, 0, stream>>>(c1_wl, c1_wr, wpk1, 32);
    wprep_k<<<(64 * 128 + 255) / 256, 256, 0, stream>>>(c2_wl, c2_wr, wpk2, 64);

    // two-level bucket sort -> csr in CSR order + rofs (no N-length hist/scan)
    thist_k<<<NT, 256, 0, stream>>>(dst, thist, E, NSB);
    toffs2_k<<<1, 256, 0, stream>>>(thist, toffs, bbase, NT, NSB, E);
    scat1_k<<<NT, 256, 0, stream>>>(src, dst, toffs, staged, E, NSB);
    scat2_k<<<NSB, 256, 0, stream>>>(bbase, staged, csr, rofs, N, E, NSB);

    conv_mfma<32, true><<<(N + 31) / 32, 256, 0, stream>>>(rofs, csr, h0u, wpk1,
                                                           c1_bl, h1u, N);
    conv_mfma<64, false><<<(N + 31) / 32, 256, 0, stream>>>(rofs, csr, h1u, wpk2,
                                                            c2_bl, h2f, N);

    pool_mlp_k<<<G, 256, 0, stream>>>(h2f, batch, N, p1w, p1b, p2w, p2b, ow, ob,
                                      (float*)d_out);
}

// Round 9
// 306.683 us; speedup vs baseline: 2.5336x; 1.2173x over previous
//
#include <hip/hip_runtime.h>

#define EPSN 1e-12f
#define TILE 8192   // edges per pass-1 tile
#define SBN 512     // nodes per coarse bucket (key = dst>>9)

using frag_ab = __attribute__((ext_vector_type(8))) short;   // 8 bf16
using frag_cd = __attribute__((ext_vector_type(4))) float;   // 4 fp32

__device__ inline unsigned short f2bf(float x) {
    union { float f; unsigned u; } v; v.f = x;
    unsigned r = v.u + 0x7fffu + ((v.u >> 16) & 1u);   // round-to-nearest-even
    return (unsigned short)(r >> 16);
}
__device__ inline float bf2f(unsigned short b) {
    union { unsigned u; float f; } v; v.u = ((unsigned)b) << 16; return v.f;
}

// ---------------- pre: h0 = relu(x @ pre_w + pre_b) -> bf16 [N,32] ------------
__global__ void pre_linear(const float* __restrict__ x, const float* __restrict__ w,
                           const float* __restrict__ b, unsigned short* __restrict__ h0,
                           int n) {
    int idx = blockIdx.x * blockDim.x + threadIdx.x;
    if (idx >= n * 32) return;
    int node = idx >> 5, j = idx & 31;
    float v = b[j];
#pragma unroll
    for (int k = 0; k < 5; ++k) v += x[node * 5 + k] * w[k * 32 + j];
    h0[idx] = f2bf(fmaxf(v, 0.f));
}

// ---------------- weight pack: B-fragment = one 16B vector load ---------------
__global__ void wprep_k(const float* __restrict__ wl, const float* __restrict__ wr,
                        unsigned short* __restrict__ wpk, int kin) {
    int kt = 2 * kin;
    int total = 64 * kt;
    int o = blockIdx.x * blockDim.x + threadIdx.x;
    if (o >= total) return;
    int j = o / kt;
    int k = o % kt;                // k = s*32 + q*8 + i
    float v = (k < kin) ? wl[k * 64 + j] : wr[(k - kin) * 64 + j];
    wpk[o] = f2bf(v);
}

// ---------------- pass 1a: per-tile histogram (bucket-major output) -----------
__global__ __launch_bounds__(256) void thist_k(const int* __restrict__ dst,
                                               int* __restrict__ thistT, int e,
                                               int nsb, int nt) {
    __shared__ int lh[SBN];
    int tid = threadIdx.x;
    for (int i = tid; i < nsb; i += 256) lh[i] = 0;
    __syncthreads();
    int base = blockIdx.x * TILE;
    int lim = min(base + TILE, e);
    for (int i = base + tid; i < lim; i += 256) atomicAdd(&lh[dst[i] >> 9], 1);
    __syncthreads();
    for (int i = tid; i < nsb; i += 256) thistT[(size_t)i * nt + blockIdx.x] = lh[i];
}

// ---------------- pass 1b-1: per-bucket scan over tiles (parallel) ------------
// Round-8's toffs2_k was a single-block kernel with a serial 196-iter loop per
// thread: 70 us of unhidden latency. Now one block per bucket scans its own
// contiguous tile-count row concurrently.
__global__ __launch_bounds__(256) void tscan_k(const int* __restrict__ thistT,
                                               int* __restrict__ toffsT,
                                               int* __restrict__ btot, int nt) {
    __shared__ int wsum[8];
    int b = blockIdx.x;
    int tid = threadIdx.x;
    int lane = tid & 63, w = tid >> 6;
    int x = (tid < nt) ? thistT[(size_t)b * nt + tid] : 0;
    int inc = x;
#pragma unroll
    for (int o = 1; o < 64; o <<= 1) {
        int t = __shfl_up(inc, o);
        if (lane >= o) inc += t;
    }
    if (lane == 63) wsum[w] = inc;
    __syncthreads();
    if (tid == 0) {
        int s = 0;
#pragma unroll
        for (int k = 0; k < 4; ++k) { int t = wsum[k]; wsum[k] = s; s += t; }
        wsum[4] = s;
    }
    __syncthreads();
    int excl = inc - x + wsum[w];
    if (tid < nt) toffsT[(size_t)b * nt + tid] = excl;
    if (tid == 0) btot[b] = wsum[4];
}

// ---------------- pass 1b-2: scan bucket totals -> bbase (tiny) ---------------
__global__ __launch_bounds__(256) void bscan_k(const int* __restrict__ btot,
                                               int* __restrict__ bbase, int nsb, int e) {
    __shared__ int wsum[8];
    int tid = threadIdx.x;
    int lane = tid & 63, w = tid >> 6;
    int x = (tid < nsb) ? btot[tid] : 0;
    int inc = x;
#pragma unroll
    for (int o = 1; o < 64; o <<= 1) {
        int t = __shfl_up(inc, o);
        if (lane >= o) inc += t;
    }
    if (lane == 63) wsum[w] = inc;
    __syncthreads();
    if (tid == 0) {
        int s = 0;
#pragma unroll
        for (int k = 0; k < 4; ++k) { int t = wsum[k]; wsum[k] = s; s += t; }
    }
    __syncthreads();
    if (tid < nsb) bbase[tid] = inc - x + wsum[w];
    if (tid == 0) bbase[nsb] = e;
}

// ---------------- pass 1c: scatter into bucket-grouped staging ----------------
__global__ __launch_bounds__(256) void scat1_k(const int* __restrict__ src,
                                               const int* __restrict__ dst,
                                               const int* __restrict__ toffsT,
                                               const int* __restrict__ bbase,
                                               int* __restrict__ staged, int e,
                                               int nsb, int nt) {
    __shared__ int cur[SBN];
    int tid = threadIdx.x;
    for (int i = tid; i < nsb; i += 256)
        cur[i] = toffsT[(size_t)i * nt + blockIdx.x] + bbase[i];
    __syncthreads();
    int base = blockIdx.x * TILE;
    int lim = min(base + TILE, e);
    for (int i = base + tid; i < lim; i += 256) {
        int d = dst[i];
        int p = atomicAdd(&cur[d >> 9], 1);
        staged[p] = (src[i] << 9) | (d & 511);   // src < 2^23, fits
    }
}

// ---------------- pass 2: per-bucket sort -> csr (CSR order) + rofs -----------
__global__ __launch_bounds__(256) void scat2_k(const int* __restrict__ bbase,
                                               const int* __restrict__ staged,
                                               int* __restrict__ csr,
                                               int* __restrict__ rofs,
                                               int n, int e, int nsb) {
    __shared__ int h[SBN];
    __shared__ int cur[SBN];
    __shared__ int wsum[8];
    int b = blockIdx.x;
    int tid = threadIdx.x;
    int lane = tid & 63, w = tid >> 6;
    int nlo = b << 9;
    int nn = n - nlo; if (nn > SBN) nn = SBN;   // live nodes in bucket
    int lo = bbase[b], hi = bbase[b + 1];
    h[tid] = 0;
    h[tid + 256] = 0;
    __syncthreads();
    for (int i = lo + tid; i < hi; i += 256) atomicAdd(&h[staged[i] & 511], 1);
    __syncthreads();
    int a0 = h[2 * tid], a1 = h[2 * tid + 1];
    int ps = a0 + a1;
    int inc = ps;
#pragma unroll
    for (int o = 1; o < 64; o <<= 1) {
        int t = __shfl_up(inc, o);
        if (lane >= o) inc += t;
    }
    if (lane == 63) wsum[w] = inc;
    __syncthreads();
    if (tid == 0) {
        int s = 0;
#pragma unroll
        for (int k = 0; k < 4; ++k) { int t = wsum[k]; wsum[k] = s; s += t; }
    }
    __syncthreads();
    int excl = inc - ps + wsum[w];
    cur[2 * tid] = excl;
    cur[2 * tid + 1] = excl + a0;
    __syncthreads();
    if (2 * tid < nn) rofs[nlo + 2 * tid] = lo + cur[2 * tid];
    if (2 * tid + 1 < nn) rofs[nlo + 2 * tid + 1] = lo + cur[2 * tid + 1];
    if (b == nsb - 1 && tid == 0) rofs[n] = e;
    __syncthreads();   // rofs must read cur before scatter mutates it
    for (int i = lo + tid; i < hi; i += 256) {
        int v = staged[i];
        int p = atomicAdd(&cur[v & 511], 1);
        csr[lo + p] = v >> 9;
    }
}

// ---------------- SAGE conv via MFMA, 32 nodes/block --------------------------
template <int KIN, bool OUTBF16>
__global__ __launch_bounds__(256) void conv_mfma(
    const int* __restrict__ rofs, const int* __restrict__ csr,
    const unsigned short* __restrict__ hin, const unsigned short* __restrict__ wpk,
    const float* __restrict__ bl, void* __restrict__ hout, int n) {
    constexpr int KT = 2 * KIN;    // concat [agg|self]
    constexpr int ST = KT + 8;     // LDS row stride in ushorts (16B-aligned rows)
    constexpr int KS = KT / 32;    // MFMA k-steps
    constexpr int LPE = KIN / 8;   // lanes per edge row (16B each)
    constexpr int EPW = 64 / LPE;  // edges per wave-load
    __shared__ unsigned short __attribute__((aligned(16))) Ab[32 * ST];
    __shared__ float __attribute__((aligned(16))) Nb[4][32];

    int w = threadIdx.x >> 6;      // wave id == j-tile
    int lane = threadIdx.x & 63;
    int quad = lane >> 4;
    int l16 = lane & 15;
    int base = blockIdx.x * 32;
    int ncol = w * 16 + l16;

    // B fragments: one 16B load each from packed weights
    frag_ab bfrag[KS];
#pragma unroll
    for (int s = 0; s < KS; ++s)
        bfrag[s] = *(const frag_ab*)&wpk[(((ncol * KS) + s) * 4 + quad) * 8];
    float bias = bl[ncol];

    // ---- gather phase: wave w fills LDS rows w*8 .. w*8+7 ----
    int grp = lane / LPE;          // edge slot within a wave-load
    int p = lane % LPE;            // 16B chunk within a row
    for (int i = 0; i < 8; ++i) {
        int li = w * 8 + i;
        int node = base + li;
        if (node >= n) break;
        int beg = rofs[node], end = rofs[node + 1];
        int cnt = end - beg;
        uint4 selfv = make_uint4(0u, 0u, 0u, 0u);
        if (grp == 1)
            selfv = *(const uint4*)&hin[(size_t)node * KIN + p * 8];
        float a0 = 0.f, a1 = 0.f, a2 = 0.f, a3 = 0.f;
        float a4 = 0.f, a5 = 0.f, a6 = 0.f, a7 = 0.f;
#pragma unroll 2
        for (int e = 0; e < cnt; e += EPW) {
            int ee = e + grp;
            bool ok = (ee < cnt);
            int s = csr[beg + (ok ? ee : 0)];
            uint4 u = *(const uint4*)&hin[(size_t)s * KIN + p * 8];
            if (ok) {
                a0 += bf2f((unsigned short)u.x); a1 += bf2f((unsigned short)(u.x >> 16));
                a2 += bf2f((unsigned short)u.y); a3 += bf2f((unsigned short)(u.y >> 16));
                a4 += bf2f((unsigned short)u.z); a5 += bf2f((unsigned short)(u.z >> 16));
                a6 += bf2f((unsigned short)u.w); a7 += bf2f((unsigned short)(u.w >> 16));
            }
        }
        float acc[8] = {a0, a1, a2, a3, a4, a5, a6, a7};
#pragma unroll
        for (int o = LPE; o < 64; o <<= 1) {
#pragma unroll
            for (int q = 0; q < 8; ++q) acc[q] += __shfl_xor(acc[q], o);
        }
        float inv = (cnt > 0) ? 1.0f / (float)cnt : 0.0f;
        if (grp == 0) {
            uint4 o4;
            o4.x = (unsigned)f2bf(acc[0] * inv) | ((unsigned)f2bf(acc[1] * inv) << 16);
            o4.y = (unsigned)f2bf(acc[2] * inv) | ((unsigned)f2bf(acc[3] * inv) << 16);
            o4.z = (unsigned)f2bf(acc[4] * inv) | ((unsigned)f2bf(acc[5] * inv) << 16);
            o4.w = (unsigned)f2bf(acc[6] * inv) | ((unsigned)f2bf(acc[7] * inv) << 16);
            *(uint4*)&Ab[li * ST + p * 8] = o4;
        } else if (grp == 1) {
            *(uint4*)&Ab[li * ST + KIN + p * 8] = selfv;
        }
    }
    __syncthreads();

    // ---- MFMA phase: wave w computes cols [w*16, w*16+16) for 2 M-tiles ----
    frag_cd acc[2];
#pragma unroll
    for (int t = 0; t < 2; ++t) acc[t] = (frag_cd){0.f, 0.f, 0.f, 0.f};
#pragma unroll
    for (int t = 0; t < 2; ++t) {
#pragma unroll
        for (int s = 0; s < KS; ++s) {
            frag_ab af = *(frag_ab*)&Ab[(t * 16 + l16) * ST + s * 32 + quad * 8];
            acc[t] = __builtin_amdgcn_mfma_f32_16x16x32_bf16(af, bfrag[s], acc[t], 0, 0, 0);
        }
    }

    // ---- epilogue: bias, per-node sumsq partials ----
    float vv[2][4];
#pragma unroll
    for (int t = 0; t < 2; ++t) {
        float q[4];
#pragma unroll
        for (int i = 0; i < 4; ++i) {
            float v = acc[t][i] + bias;   // D row = quad*4+i (node), col = l16
            vv[t][i] = v;
            q[i] = v * v;
        }
#pragma unroll
        for (int o = 1; o < 16; o <<= 1) {
#pragma unroll
            for (int i = 0; i < 4; ++i) q[i] += __shfl_xor(q[i], o);
        }
        if (l16 == 0) {
            float4 qq = make_float4(q[0], q[1], q[2], q[3]);
            *(float4*)&Nb[w][t * 16 + quad * 4] = qq;
        }
    }
    __syncthreads();

#pragma unroll
    for (int t = 0; t < 2; ++t) {
        float s0 = 0.f, s1 = 0.f, s2 = 0.f, s3 = 0.f;
#pragma unroll
        for (int ww = 0; ww < 4; ++ww) {
            float4 xq = *(const float4*)&Nb[ww][t * 16 + quad * 4];
            s0 += xq.x; s1 += xq.y; s2 += xq.z; s3 += xq.w;
        }
        float ss[4] = {s0, s1, s2, s3};
#pragma unroll
        for (int i = 0; i < 4; ++i) {
            int node = base + t * 16 + quad * 4 + i;
            if (node < n) {
                float nv = fmaxf(sqrtf(ss[i]), EPSN);
                float outv = fmaxf(vv[t][i] / nv, 0.f);
                if (OUTBF16)
                    ((unsigned short*)hout)[(size_t)node * 64 + ncol] = f2bf(outv);
                else
                    ((float*)hout)[(size_t)node * 64 + ncol] = outv;
            }
        }
    }
}

// ---------------- fused pool (batch sorted) + head MLP ------------------------
__global__ __launch_bounds__(256) void pool_mlp_k(
    const float* __restrict__ h, const int* __restrict__ batch, int n,
    const float* __restrict__ p1w, const float* __restrict__ p1b,
    const float* __restrict__ p2w, const float* __restrict__ p2b,
    const float* __restrict__ ow, const float* __restrict__ ob,
    float* __restrict__ out) {
    __shared__ float part[4][64];
    __shared__ float gmean[64];
    __shared__ float a1[64];
    __shared__ float a2[16];
    int g = blockIdx.x;
    int w = threadIdx.x >> 6, j = threadIdx.x & 63;
    int lo = 0, hi = n;
    while (lo < hi) { int m = (lo + hi) >> 1; if (batch[m] < g) lo = m + 1; else hi = m; }
    int start = lo;
    hi = n;
    while (lo < hi) { int m = (lo + hi) >> 1; if (batch[m] < g + 1) lo = m + 1; else hi = m; }
    int end = lo;
    float acc = 0.f;
    for (int node = start + w; node < end; node += 4)
        acc += h[(size_t)node * 64 + j];
    part[w][j] = acc;
    __syncthreads();
    if (w == 0) {
        float s = part[0][j] + part[1][j] + part[2][j] + part[3][j];
        float c = (float)(end - start);
        gmean[j] = s / fmaxf(c, 1.0f);
    }
    __syncthreads();
    if (w == 0) {
        float v = p1b[j];
#pragma unroll 8
        for (int k = 0; k < 64; ++k) v = fmaf(gmean[k], p1w[k * 64 + j], v);
        a1[j] = fmaxf(v, 0.f);
    }
    __syncthreads();
    if (w == 0 && j < 16) {
        float v2 = p2b[j];
#pragma unroll 8
        for (int k = 0; k < 64; ++k) v2 = fmaf(a1[k], p2w[k * 16 + j], v2);
        a2[j] = fmaxf(v2, 0.f);
    }
    __syncthreads();
    if (threadIdx.x == 0) {
        float v3 = ob[0];
#pragma unroll
        for (int k = 0; k < 16; ++k) v3 = fmaf(a2[k], ow[k], v3);
        out[g] = v3;
    }
}

extern "C" void kernel_launch(void* const* d_in, const int* in_sizes, int n_in,
                              void* d_out, int out_size, void* d_ws, size_t ws_size,
                              hipStream_t stream) {
    const float* x     = (const float*)d_in[0];
    const int*   ei    = (const int*)d_in[1];
    const int*   batch = (const int*)d_in[2];
    const float* pre_w = (const float*)d_in[4];
    const float* pre_b = (const float*)d_in[5];
    const float* c1_wl = (const float*)d_in[6];
    const float* c1_bl = (const float*)d_in[7];
    const float* c1_wr = (const float*)d_in[8];
    const float* c2_wl = (const float*)d_in[9];
    const float* c2_bl = (const float*)d_in[10];
    const float* c2_wr = (const float*)d_in[11];
    const float* p1w   = (const float*)d_in[12];
    const float* p1b   = (const float*)d_in[13];
    const float* p2w   = (const float*)d_in[14];
    const float* p2b   = (const float*)d_in[15];
    const float* ow    = (const float*)d_in[16];
    const float* ob    = (const float*)d_in[17];

    const int N = in_sizes[0] / 5;
    const int E = in_sizes[1] / 2;
    const int G = out_size;
    const int NT = (E + TILE - 1) / TILE; // pass-1 tiles (196 <= 256)
    const int NSB = (N + SBN - 1) / SBN;  // coarse buckets (196 <= 256)
    const int* src = ei;
    const int* dst = ei + E;

    // workspace layout
    float* h2f = (float*)d_ws;                                      // N*64 f32
    unsigned short* h0u = (unsigned short*)(h2f + (size_t)N * 64);  // N*32 bf16
    unsigned short* h1u = h0u + (size_t)N * 32;                     // N*64 bf16
    unsigned short* wpk1 = h1u + (size_t)N * 64;                    // 64*64
    unsigned short* wpk2 = wpk1 + 64 * 64;                          // 64*128
    int* rofs    = (int*)(wpk2 + 64 * 128);                         // N+1
    int* bbase   = rofs + N + 1;                                    // NSB+1
    int* btot    = bbase + NSB + 1;                                 // NSB
    int* thistT  = btot + NSB;                                      // NSB*NT
    int* toffsT  = thistT + (size_t)NSB * NT;                       // NSB*NT
    int* staged  = toffsT + (size_t)NSB * NT;                       // E
    int* csr     = staged + E;                                      // E

    pre_linear<<<(N * 32 + 255) / 256, 256, 0, stream>>>(x, pre_w, pre_b, h0u, N);
    wprep_k<<<(64 * 64 + 255) / 256, 256, 0, stream>>>(c1_wl, c1_wr, wpk1, 32);
    wprep_k<<<(64 * 128 + 255) / 256, 256, 0, stream>>>(c2_wl, c2_wr, wpk2, 64);

    // two-level bucket sort -> csr in CSR order + rofs
    thist_k<<<NT, 256, 0, stream>>>(dst, thistT, E, NSB, NT);
    tscan_k<<<NSB, 256, 0, stream>>>(thistT, toffsT, btot, NT);
    bscan_k<<<1, 256, 0, stream>>>(btot, bbase, NSB, E);
    scat1_k<<<NT, 256, 0, stream>>>(src, dst, toffsT, bbase, staged, E, NSB, NT);
    scat2_k<<<NSB, 256, 0, stream>>>(bbase, staged, csr, rofs, N, E, NSB);

    conv_mfma<32, true><<<(N + 31) / 32, 256, 0, stream>>>(rofs, csr, h0u, wpk1,
                                                           c1_bl, h1u, N);
    conv_mfma<64, false><<<(N + 31) / 32, 256, 0, stream>>>(rofs, csr, h1u, wpk2,
                                                            c2_bl, h2f, N);

    pool_mlp_k<<<G, 256, 0, stream>>>(h2f, batch, N, p1w, p1b, p2w, p2b, ow, ob,
                                      (float*)d_out);
}

// Round 11
// 302.077 us; speedup vs baseline: 2.5722x; 1.0152x over previous
//
#include <hip/hip_runtime.h>

#define EPSN 1e-12f
#define TILE 8192   // edges per pass-1 tile
#define SBN 512     // nodes per coarse bucket (key = dst>>9)

using frag_ab = __attribute__((ext_vector_type(8))) short;   // 8 bf16
using frag_cd = __attribute__((ext_vector_type(4))) float;   // 4 fp32

__device__ inline unsigned short f2bf(float x) {
    union { float f; unsigned u; } v; v.f = x;
    unsigned r = v.u + 0x7fffu + ((v.u >> 16) & 1u);   // round-to-nearest-even
    return (unsigned short)(r >> 16);
}
__device__ inline float bf2f(unsigned short b) {
    union { unsigned u; float f; } v; v.u = ((unsigned)b) << 16; return v.f;
}
__device__ inline void upadd(uint4 u, float* a) {
    a[0] += bf2f((unsigned short)u.x); a[1] += bf2f((unsigned short)(u.x >> 16));
    a[2] += bf2f((unsigned short)u.y); a[3] += bf2f((unsigned short)(u.y >> 16));
    a[4] += bf2f((unsigned short)u.z); a[5] += bf2f((unsigned short)(u.z >> 16));
    a[6] += bf2f((unsigned short)u.w); a[7] += bf2f((unsigned short)(u.w >> 16));
}

// ---------------- pre: h0 = relu(x @ pre_w + pre_b) -> bf16 [N,32] ------------
__global__ void pre_linear(const float* __restrict__ x, const float* __restrict__ w,
                           const float* __restrict__ b, unsigned short* __restrict__ h0,
                           int n) {
    int idx = blockIdx.x * blockDim.x + threadIdx.x;
    if (idx >= n * 32) return;
    int node = idx >> 5, j = idx & 31;
    float v = b[j];
#pragma unroll
    for (int k = 0; k < 5; ++k) v += x[node * 5 + k] * w[k * 32 + j];
    h0[idx] = f2bf(fmaxf(v, 0.f));
}

// ---------------- weight pack: B-fragment = one 16B vector load ---------------
__global__ void wprep_k(const float* __restrict__ wl, const float* __restrict__ wr,
                        unsigned short* __restrict__ wpk, int kin) {
    int kt = 2 * kin;
    int total = 64 * kt;
    int o = blockIdx.x * blockDim.x + threadIdx.x;
    if (o >= total) return;
    int j = o / kt;
    int k = o % kt;                // k = s*32 + q*8 + i
    float v = (k < kin) ? wl[k * 64 + j] : wr[(k - kin) * 64 + j];
    wpk[o] = f2bf(v);
}

// ---------------- pass 1a: per-tile histogram (bucket-major output) -----------
__global__ __launch_bounds__(256) void thist_k(const int* __restrict__ dst,
                                               int* __restrict__ thistT, int e,
                                               int nsb, int nt) {
    __shared__ int lh[SBN];
    int tid = threadIdx.x;
    for (int i = tid; i < nsb; i += 256) lh[i] = 0;
    __syncthreads();
    int base = blockIdx.x * TILE;
    int lim = min(base + TILE, e);
    for (int i = base + tid; i < lim; i += 256) atomicAdd(&lh[dst[i] >> 9], 1);
    __syncthreads();
    for (int i = tid; i < nsb; i += 256) thistT[(size_t)i * nt + blockIdx.x] = lh[i];
}

// ---------------- pass 1b-1: per-bucket scan over tiles (parallel) ------------
__global__ __launch_bounds__(256) void tscan_k(const int* __restrict__ thistT,
                                               int* __restrict__ toffsT,
                                               int* __restrict__ btot, int nt) {
    __shared__ int wsum[8];
    int b = blockIdx.x;
    int tid = threadIdx.x;
    int lane = tid & 63, w = tid >> 6;
    int x = (tid < nt) ? thistT[(size_t)b * nt + tid] : 0;
    int inc = x;
#pragma unroll
    for (int o = 1; o < 64; o <<= 1) {
        int t = __shfl_up(inc, o);
        if (lane >= o) inc += t;
    }
    if (lane == 63) wsum[w] = inc;
    __syncthreads();
    if (tid == 0) {
        int s = 0;
#pragma unroll
        for (int k = 0; k < 4; ++k) { int t = wsum[k]; wsum[k] = s; s += t; }
        wsum[4] = s;
    }
    __syncthreads();
    int excl = inc - x + wsum[w];
    if (tid < nt) toffsT[(size_t)b * nt + tid] = excl;
    if (tid == 0) btot[b] = wsum[4];
}

// ---------------- pass 1b-2: scan bucket totals -> bbase (tiny) ---------------
__global__ __launch_bounds__(256) void bscan_k(const int* __restrict__ btot,
                                               int* __restrict__ bbase, int nsb, int e) {
    __shared__ int wsum[8];
    int tid = threadIdx.x;
    int lane = tid & 63, w = tid >> 6;
    int x = (tid < nsb) ? btot[tid] : 0;
    int inc = x;
#pragma unroll
    for (int o = 1; o < 64; o <<= 1) {
        int t = __shfl_up(inc, o);
        if (lane >= o) inc += t;
    }
    if (lane == 63) wsum[w] = inc;
    __syncthreads();
    if (tid == 0) {
        int s = 0;
#pragma unroll
        for (int k = 0; k < 4; ++k) { int t = wsum[k]; wsum[k] = s; s += t; }
    }
    __syncthreads();
    if (tid < nsb) bbase[tid] = inc - x + wsum[w];
    if (tid == 0) bbase[nsb] = e;
}

// ---------------- pass 1c: scatter into bucket-grouped staging ----------------
__global__ __launch_bounds__(256) void scat1_k(const int* __restrict__ src,
                                               const int* __restrict__ dst,
                                               const int* __restrict__ toffsT,
                                               const int* __restrict__ bbase,
                                               int* __restrict__ staged, int e,
                                               int nsb, int nt) {
    __shared__ int cur[SBN];
    int tid = threadIdx.x;
    for (int i = tid; i < nsb; i += 256)
        cur[i] = toffsT[(size_t)i * nt + blockIdx.x] + bbase[i];
    __syncthreads();
    int base = blockIdx.x * TILE;
    int lim = min(base + TILE, e);
    for (int i = base + tid; i < lim; i += 256) {
        int d = dst[i];
        int p = atomicAdd(&cur[d >> 9], 1);
        staged[p] = (src[i] << 9) | (d & 511);   // src < 2^23, fits
    }
}

// ---------------- pass 2: per-bucket sort -> csr (CSR order) + rofs -----------
__global__ __launch_bounds__(256) void scat2_k(const int* __restrict__ bbase,
                                               const int* __restrict__ staged,
                                               int* __restrict__ csr,
                                               int* __restrict__ rofs,
                                               int n, int e, int nsb) {
    __shared__ int h[SBN];
    __shared__ int cur[SBN];
    __shared__ int wsum[8];
    int b = blockIdx.x;
    int tid = threadIdx.x;
    int lane = tid & 63, w = tid >> 6;
    int nlo = b << 9;
    int nn = n - nlo; if (nn > SBN) nn = SBN;   // live nodes in bucket
    int lo = bbase[b], hi = bbase[b + 1];
    h[tid] = 0;
    h[tid + 256] = 0;
    __syncthreads();
    for (int i = lo + tid; i < hi; i += 256) atomicAdd(&h[staged[i] & 511], 1);
    __syncthreads();
    int a0 = h[2 * tid], a1 = h[2 * tid + 1];
    int ps = a0 + a1;
    int inc = ps;
#pragma unroll
    for (int o = 1; o < 64; o <<= 1) {
        int t = __shfl_up(inc, o);
        if (lane >= o) inc += t;
    }
    if (lane == 63) wsum[w] = inc;
    __syncthreads();
    if (tid == 0) {
        int s = 0;
#pragma unroll
        for (int k = 0; k < 4; ++k) { int t = wsum[k]; wsum[k] = s; s += t; }
    }
    __syncthreads();
    int excl = inc - ps + wsum[w];
    cur[2 * tid] = excl;
    cur[2 * tid + 1] = excl + a0;
    __syncthreads();
    if (2 * tid < nn) rofs[nlo + 2 * tid] = lo + cur[2 * tid];
    if (2 * tid + 1 < nn) rofs[nlo + 2 * tid + 1] = lo + cur[2 * tid + 1];
    if (b == nsb - 1 && tid == 0) rofs[n] = e;
    __syncthreads();   // rofs must read cur before scatter mutates it
    for (int i = lo + tid; i < hi; i += 256) {
        int v = staged[i];
        int p = atomicAdd(&cur[v & 511], 1);
        csr[lo + p] = v >> 9;
    }
}

// ---------------- SAGE conv via MFMA, 32 nodes/block --------------------------
// Gather: node-PAIR interleave (2 independent edge streams per wave) +
// block-wide rofs preload in LDS. Self rows: grp 1 loads+writes selfA,
// grp 3 loads+writes selfB (round-10 bug: grp 1 loaded selfB but grp 3 wrote
// it -> odd nodes lost their self term).
// POOL=true (conv2): epilogue reduces relu'd rows per graph segment (batch
// sorted) and atomicAdds into L2-resident sg[g*64+col].
template <int KIN, bool POOL>
__global__ __launch_bounds__(256) void conv_mfma(
    const int* __restrict__ rofs, const int* __restrict__ csr,
    const unsigned short* __restrict__ hin, const unsigned short* __restrict__ wpk,
    const float* __restrict__ bl, const int* __restrict__ batch,
    float* __restrict__ sg, unsigned short* __restrict__ hout, int n) {
    constexpr int KT = 2 * KIN;    // concat [agg|self]
    constexpr int ST = KT + 8;     // LDS row stride in ushorts (16B-aligned rows)
    constexpr int KS = KT / 32;    // MFMA k-steps
    constexpr int LPE = KIN / 8;   // lanes per edge row (16B each)
    constexpr int EPW = 64 / LPE;  // edges per wave-load
    __shared__ unsigned short __attribute__((aligned(16))) Ab[32 * ST];
    __shared__ float __attribute__((aligned(16))) Nb[4][32];
    __shared__ int ro[33];
    __shared__ int sb[32];

    int tid = threadIdx.x;
    int w = tid >> 6;              // wave id == j-tile
    int lane = tid & 63;
    int quad = lane >> 4;
    int l16 = lane & 15;
    int base = blockIdx.x * 32;
    int ncol = w * 16 + l16;

    if (tid < 33) ro[tid] = rofs[min(base + tid, n)];
    if (POOL && tid < 32) {
        int nd = base + tid;
        sb[tid] = (nd < n) ? batch[nd] : -1;
    }

    // B fragments: one 16B load each from packed weights
    frag_ab bfrag[KS];
#pragma unroll
    for (int s = 0; s < KS; ++s)
        bfrag[s] = *(const frag_ab*)&wpk[(((ncol * KS) + s) * 4 + quad) * 8];
    float bias = bl[ncol];
    __syncthreads();

    // ---- gather phase: wave w fills LDS rows w*8 .. w*8+7, node pairs ----
    int grp = lane / LPE;          // edge slot within a wave-load
    int p = lane % LPE;            // 16B chunk within a row
    for (int i = 0; i < 8; i += 2) {
        int liA = w * 8 + i, liB = liA + 1;
        int ndA = base + liA, ndB = base + liB;
        bool vA = ndA < n, vB = ndB < n;
        int begA = ro[liA], cntA = vA ? ro[liA + 1] - begA : 0;
        int begB = ro[liB], cntB = vB ? ro[liB + 1] - begB : 0;
        uint4 selfA = make_uint4(0u, 0u, 0u, 0u), selfB = selfA;
        if (grp == 1 && vA) selfA = *(const uint4*)&hin[(size_t)ndA * KIN + p * 8];
        if (grp == 3 && vB) selfB = *(const uint4*)&hin[(size_t)ndB * KIN + p * 8];
        float aA[8] = {0.f}, aB[8] = {0.f};
        int rounds = max((cntA + EPW - 1) / EPW, (cntB + EPW - 1) / EPW);
        for (int r = 0; r < rounds; ++r) {
            int e = r * EPW + grp;
            bool okA = e < cntA, okB = e < cntB;
            int sA = csr[okA ? begA + e : 0];
            int sB = csr[okB ? begB + e : 0];
            uint4 uA = *(const uint4*)&hin[(size_t)sA * KIN + p * 8];
            uint4 uB = *(const uint4*)&hin[(size_t)sB * KIN + p * 8];
            if (okA) upadd(uA, aA);
            if (okB) upadd(uB, aB);
        }
#pragma unroll
        for (int o = LPE; o < 64; o <<= 1) {
#pragma unroll
            for (int q = 0; q < 8; ++q) {
                aA[q] += __shfl_xor(aA[q], o);
                aB[q] += __shfl_xor(aB[q], o);
            }
        }
        float invA = (cntA > 0) ? 1.0f / (float)cntA : 0.0f;
        float invB = (cntB > 0) ? 1.0f / (float)cntB : 0.0f;
        if (grp == 0) {
            uint4 o4;
            o4.x = (unsigned)f2bf(aA[0] * invA) | ((unsigned)f2bf(aA[1] * invA) << 16);
            o4.y = (unsigned)f2bf(aA[2] * invA) | ((unsigned)f2bf(aA[3] * invA) << 16);
            o4.z = (unsigned)f2bf(aA[4] * invA) | ((unsigned)f2bf(aA[5] * invA) << 16);
            o4.w = (unsigned)f2bf(aA[6] * invA) | ((unsigned)f2bf(aA[7] * invA) << 16);
            *(uint4*)&Ab[liA * ST + p * 8] = o4;
        } else if (grp == 1) {
            *(uint4*)&Ab[liA * ST + KIN + p * 8] = selfA;
        } else if (grp == 2) {
            uint4 o4;
            o4.x = (unsigned)f2bf(aB[0] * invB) | ((unsigned)f2bf(aB[1] * invB) << 16);
            o4.y = (unsigned)f2bf(aB[2] * invB) | ((unsigned)f2bf(aB[3] * invB) << 16);
            o4.z = (unsigned)f2bf(aB[4] * invB) | ((unsigned)f2bf(aB[5] * invB) << 16);
            o4.w = (unsigned)f2bf(aB[6] * invB) | ((unsigned)f2bf(aB[7] * invB) << 16);
            *(uint4*)&Ab[liB * ST + p * 8] = o4;
        } else if (grp == 3) {
            *(uint4*)&Ab[liB * ST + KIN + p * 8] = selfB;
        }
    }
    __syncthreads();

    // ---- MFMA phase: wave w computes cols [w*16, w*16+16) for 2 M-tiles ----
    frag_cd acc[2];
#pragma unroll
    for (int t = 0; t < 2; ++t) acc[t] = (frag_cd){0.f, 0.f, 0.f, 0.f};
#pragma unroll
    for (int t = 0; t < 2; ++t) {
#pragma unroll
        for (int s = 0; s < KS; ++s) {
            frag_ab af = *(frag_ab*)&Ab[(t * 16 + l16) * ST + s * 32 + quad * 8];
            acc[t] = __builtin_amdgcn_mfma_f32_16x16x32_bf16(af, bfrag[s], acc[t], 0, 0, 0);
        }
    }

    // ---- epilogue: bias, per-node L2 norm (cross-wave via LDS), relu ----
    float vv[2][4];
#pragma unroll
    for (int t = 0; t < 2; ++t) {
        float q[4];
#pragma unroll
        for (int i = 0; i < 4; ++i) {
            float v = acc[t][i] + bias;   // D row = quad*4+i (node), col = l16
            vv[t][i] = v;
            q[i] = v * v;
        }
#pragma unroll
        for (int o = 1; o < 16; o <<= 1) {
#pragma unroll
            for (int i = 0; i < 4; ++i) q[i] += __shfl_xor(q[i], o);
        }
        if (l16 == 0) {
            float4 qq = make_float4(q[0], q[1], q[2], q[3]);
            *(float4*)&Nb[w][t * 16 + quad * 4] = qq;
        }
    }
    __syncthreads();

    float pv[2][4];
#pragma unroll
    for (int t = 0; t < 2; ++t) {
        float s0 = 0.f, s1 = 0.f, s2 = 0.f, s3 = 0.f;
#pragma unroll
        for (int ww = 0; ww < 4; ++ww) {
            float4 xq = *(const float4*)&Nb[ww][t * 16 + quad * 4];
            s0 += xq.x; s1 += xq.y; s2 += xq.z; s3 += xq.w;
        }
        float ss[4] = {s0, s1, s2, s3};
#pragma unroll
        for (int i = 0; i < 4; ++i) {
            float nv = fmaxf(sqrtf(ss[i]), EPSN);
            pv[t][i] = fmaxf(vv[t][i] / nv, 0.f);
        }
    }

    if (!POOL) {
#pragma unroll
        for (int t = 0; t < 2; ++t)
#pragma unroll
            for (int i = 0; i < 4; ++i) {
                int node = base + t * 16 + quad * 4 + i;
                if (node < n)
                    hout[(size_t)node * 64 + ncol] = f2bf(pv[t][i]);
            }
    } else {
        // per-graph-segment sums; batch sorted -> g in [g0,g1], small span
        int g0 = sb[0];
        int g1 = sb[min(31, n - 1 - base)];
        for (int g = g0; g <= g1; ++g) {
            float s = 0.f;
#pragma unroll
            for (int t = 0; t < 2; ++t)
#pragma unroll
                for (int i = 0; i < 4; ++i)
                    if (sb[t * 16 + quad * 4 + i] == g) s += pv[t][i];
            s += __shfl_xor(s, 16);
            s += __shfl_xor(s, 32);
            if (quad == 0) atomicAdd(&sg[(size_t)g * 64 + ncol], s);
        }
    }
}

// ---------------- head MLP per graph (counts via binary search) ---------------
__global__ __launch_bounds__(64) void mlp_k(
    const float* __restrict__ sg, const int* __restrict__ batch, int n,
    const float* __restrict__ p1w, const float* __restrict__ p1b,
    const float* __restrict__ p2w, const float* __restrict__ p2b,
    const float* __restrict__ ow, const float* __restrict__ ob,
    float* __restrict__ out) {
    __shared__ float gmean[64];
    __shared__ float a1[64];
    __shared__ float a2[16];
    int g = blockIdx.x;
    int j = threadIdx.x;
    int lo = 0, hi = n;
    while (lo < hi) { int m = (lo + hi) >> 1; if (batch[m] < g) lo = m + 1; else hi = m; }
    int start = lo;
    hi = n;
    while (lo < hi) { int m = (lo + hi) >> 1; if (batch[m] < g + 1) lo = m + 1; else hi = m; }
    float c = (float)(lo - start);
    gmean[j] = sg[(size_t)g * 64 + j] / fmaxf(c, 1.0f);
    __syncthreads();
    float v = p1b[j];
#pragma unroll 8
    for (int k = 0; k < 64; ++k) v = fmaf(gmean[k], p1w[k * 64 + j], v);
    a1[j] = fmaxf(v, 0.f);
    __syncthreads();
    if (j < 16) {
        float v2 = p2b[j];
#pragma unroll 8
        for (int k = 0; k < 64; ++k) v2 = fmaf(a1[k], p2w[k * 16 + j], v2);
        a2[j] = fmaxf(v2, 0.f);
    }
    __syncthreads();
    if (j == 0) {
        float v3 = ob[0];
#pragma unroll
        for (int k = 0; k < 16; ++k) v3 = fmaf(a2[k], ow[k], v3);
        out[g] = v3;
    }
}

extern "C" void kernel_launch(void* const* d_in, const int* in_sizes, int n_in,
                              void* d_out, int out_size, void* d_ws, size_t ws_size,
                              hipStream_t stream) {
    const float* x     = (const float*)d_in[0];
    const int*   ei    = (const int*)d_in[1];
    const int*   batch = (const int*)d_in[2];
    const float* pre_w = (const float*)d_in[4];
    const float* pre_b = (const float*)d_in[5];
    const float* c1_wl = (const float*)d_in[6];
    const float* c1_bl = (const float*)d_in[7];
    const float* c1_wr = (const float*)d_in[8];
    const float* c2_wl = (const float*)d_in[9];
    const float* c2_bl = (const float*)d_in[10];
    const float* c2_wr = (const float*)d_in[11];
    const float* p1w   = (const float*)d_in[12];
    const float* p1b   = (const float*)d_in[13];
    const float* p2w   = (const float*)d_in[14];
    const float* p2b   = (const float*)d_in[15];
    const float* ow    = (const float*)d_in[16];
    const float* ob    = (const float*)d_in[17];

    const int N = in_sizes[0] / 5;
    const int E = in_sizes[1] / 2;
    const int G = out_size;
    const int NT = (E + TILE - 1) / TILE; // pass-1 tiles (196 <= 256)
    const int NSB = (N + SBN - 1) / SBN;  // coarse buckets (196 <= 256)
    const int* src = ei;
    const int* dst = ei + E;

    // workspace layout
    unsigned short* h0u = (unsigned short*)d_ws;                    // N*32 bf16
    unsigned short* h1u = h0u + (size_t)N * 32;                     // N*64 bf16
    unsigned short* wpk1 = h1u + (size_t)N * 64;                    // 64*64
    unsigned short* wpk2 = wpk1 + 64 * 64;                          // 64*128
    float* sg    = (float*)(wpk2 + 64 * 128);                       // G*64
    int* rofs    = (int*)(sg + (size_t)G * 64);                     // N+1
    int* bbase   = rofs + N + 1;                                    // NSB+1
    int* btot    = bbase + NSB + 1;                                 // NSB
    int* thistT  = btot + NSB;                                      // NSB*NT
    int* toffsT  = thistT + (size_t)NSB * NT;                       // NSB*NT
    int* staged  = toffsT + (size_t)NSB * NT;                       // E
    int* csr     = staged + E;                                      // E

    hipMemsetAsync(sg, 0, (size_t)G * 64 * sizeof(float), stream);

    pre_linear<<<(N * 32 + 255) / 256, 256, 0, stream>>>(x, pre_w, pre_b, h0u, N);
    wprep_k<<<(64 * 64 + 255) / 256, 256, 0, stream>>>(c1_wl, c1_wr, wpk1, 32);
    wprep_k<<<(64 * 128 + 255) / 256, 256, 0, stream>>>(c2_wl, c2_wr, wpk2, 64);

    // two-level bucket sort -> csr in CSR order + rofs
    thist_k<<<NT, 256, 0, stream>>>(dst, thistT, E, NSB, NT);
    tscan_k<<<NSB, 256, 0, stream>>>(thistT, toffsT, btot, NT);
    bscan_k<<<1, 256, 0, stream>>>(btot, bbase, NSB, E);
    scat1_k<<<NT, 256, 0, stream>>>(src, dst, toffsT, bbase, staged, E, NSB, NT);
    scat2_k<<<NSB, 256, 0, stream>>>(bbase, staged, csr, rofs, N, E, NSB);

    conv_mfma<32, false><<<(N + 31) / 32, 256, 0, stream>>>(
        rofs, csr, h0u, wpk1, c1_bl, batch, sg, h1u, N);
    conv_mfma<64, true><<<(N + 31) / 32, 256, 0, stream>>>(
        rofs, csr, h1u, wpk2, c2_bl, batch, sg, nullptr, N);

    mlp_k<<<G, 64, 0, stream>>>(sg, batch, N, p1w, p1b, p2w, p2b, ow, ob,
                                (float*)d_out);
}

// Round 12
// 287.037 us; speedup vs baseline: 2.7070x; 1.0524x over previous
//
#include <hip/hip_runtime.h>

#define EPSN 1e-12f
#define TILE 8192   // edges per pass-1 tile
#define SBN 512     // nodes per coarse bucket (key = dst>>9)

using frag_ab = __attribute__((ext_vector_type(8))) short;   // 8 bf16
using frag_cd = __attribute__((ext_vector_type(4))) float;   // 4 fp32

__device__ inline unsigned short f2bf(float x) {
    union { float f; unsigned u; } v; v.f = x;
    unsigned r = v.u + 0x7fffu + ((v.u >> 16) & 1u);   // round-to-nearest-even
    return (unsigned short)(r >> 16);
}
__device__ inline float bf2f(unsigned short b) {
    union { unsigned u; float f; } v; v.u = ((unsigned)b) << 16; return v.f;
}
__device__ inline void upadd(uint4 u, float* a) {
    a[0] += bf2f((unsigned short)u.x); a[1] += bf2f((unsigned short)(u.x >> 16));
    a[2] += bf2f((unsigned short)u.y); a[3] += bf2f((unsigned short)(u.y >> 16));
    a[4] += bf2f((unsigned short)u.z); a[5] += bf2f((unsigned short)(u.z >> 16));
    a[6] += bf2f((unsigned short)u.w); a[7] += bf2f((unsigned short)(u.w >> 16));
}

// ---------------- pre: h0 = relu(x @ pre_w + pre_b) -> bf16 [N,32] ------------
__global__ void pre_linear(const float* __restrict__ x, const float* __restrict__ w,
                           const float* __restrict__ b, unsigned short* __restrict__ h0,
                           int n) {
    int idx = blockIdx.x * blockDim.x + threadIdx.x;
    if (idx >= n * 32) return;
    int node = idx >> 5, j = idx & 31;
    float v = b[j];
#pragma unroll
    for (int k = 0; k < 5; ++k) v += x[node * 5 + k] * w[k * 32 + j];
    h0[idx] = f2bf(fmaxf(v, 0.f));
}

// ---------------- fused prep: pack both weight sets + zero sg -----------------
// wpk layout: o = (((j*KS)+s)*4+q)*8+i holds Wcat[s*32+q*8+i][j], Wcat=[wl;wr]
__global__ void prep_k(const float* __restrict__ w1l, const float* __restrict__ w1r,
                       unsigned short* __restrict__ wpk1,
                       const float* __restrict__ w2l, const float* __restrict__ w2r,
                       unsigned short* __restrict__ wpk2,
                       float* __restrict__ sg, int gtot) {
    int idx = blockIdx.x * blockDim.x + threadIdx.x;
    if (idx < 64 * 64) {                       // conv1: kt=64
        int j = idx / 64, k = idx % 64;
        float v = (k < 32) ? w1l[k * 64 + j] : w1r[(k - 32) * 64 + j];
        wpk1[idx] = f2bf(v);
    } else if (idx < 64 * 64 + 64 * 128) {     // conv2: kt=128
        int o = idx - 64 * 64;
        int j = o / 128, k = o % 128;
        float v = (k < 64) ? w2l[k * 64 + j] : w2r[(k - 64) * 64 + j];
        wpk2[o] = f2bf(v);
    } else {
        int o = idx - 64 * 64 - 64 * 128;
        if (o < gtot) sg[o] = 0.f;
    }
}

// ---------------- pass 1a: per-tile histogram (bucket-major output) -----------
__global__ __launch_bounds__(256) void thist_k(const int* __restrict__ dst,
                                               int* __restrict__ thistT, int e,
                                               int nsb, int nt) {
    __shared__ int lh[SBN];
    int tid = threadIdx.x;
    for (int i = tid; i < nsb; i += 256) lh[i] = 0;
    __syncthreads();
    int base = blockIdx.x * TILE;
    int lim = min(base + TILE, e);
    for (int i = base + tid; i < lim; i += 256) atomicAdd(&lh[dst[i] >> 9], 1);
    __syncthreads();
    for (int i = tid; i < nsb; i += 256) thistT[(size_t)i * nt + blockIdx.x] = lh[i];
}

// ---------------- pass 1b-1: per-bucket scan over tiles (parallel) ------------
__global__ __launch_bounds__(256) void tscan_k(const int* __restrict__ thistT,
                                               int* __restrict__ toffsT,
                                               int* __restrict__ btot, int nt) {
    __shared__ int wsum[8];
    int b = blockIdx.x;
    int tid = threadIdx.x;
    int lane = tid & 63, w = tid >> 6;
    int x = (tid < nt) ? thistT[(size_t)b * nt + tid] : 0;
    int inc = x;
#pragma unroll
    for (int o = 1; o < 64; o <<= 1) {
        int t = __shfl_up(inc, o);
        if (lane >= o) inc += t;
    }
    if (lane == 63) wsum[w] = inc;
    __syncthreads();
    if (tid == 0) {
        int s = 0;
#pragma unroll
        for (int k = 0; k < 4; ++k) { int t = wsum[k]; wsum[k] = s; s += t; }
        wsum[4] = s;
    }
    __syncthreads();
    int excl = inc - x + wsum[w];
    if (tid < nt) toffsT[(size_t)b * nt + tid] = excl;
    if (tid == 0) btot[b] = wsum[4];
}

// ---------------- pass 1b-2: scan bucket totals -> bbase (tiny) ---------------
__global__ __launch_bounds__(256) void bscan_k(const int* __restrict__ btot,
                                               int* __restrict__ bbase, int nsb, int e) {
    __shared__ int wsum[8];
    int tid = threadIdx.x;
    int lane = tid & 63, w = tid >> 6;
    int x = (tid < nsb) ? btot[tid] : 0;
    int inc = x;
#pragma unroll
    for (int o = 1; o < 64; o <<= 1) {
        int t = __shfl_up(inc, o);
        if (lane >= o) inc += t;
    }
    if (lane == 63) wsum[w] = inc;
    __syncthreads();
    if (tid == 0) {
        int s = 0;
#pragma unroll
        for (int k = 0; k < 4; ++k) { int t = wsum[k]; wsum[k] = s; s += t; }
    }
    __syncthreads();
    if (tid < nsb) bbase[tid] = inc - x + wsum[w];
    if (tid == 0) bbase[nsb] = e;
}

// ---------------- pass 1c: scatter into bucket-grouped staging ----------------
__global__ __launch_bounds__(256) void scat1_k(const int* __restrict__ src,
                                               const int* __restrict__ dst,
                                               const int* __restrict__ toffsT,
                                               const int* __restrict__ bbase,
                                               int* __restrict__ staged, int e,
                                               int nsb, int nt) {
    __shared__ int cur[SBN];
    int tid = threadIdx.x;
    for (int i = tid; i < nsb; i += 256)
        cur[i] = toffsT[(size_t)i * nt + blockIdx.x] + bbase[i];
    __syncthreads();
    int base = blockIdx.x * TILE;
    int lim = min(base + TILE, e);
    for (int i = base + tid; i < lim; i += 256) {
        int d = dst[i];
        int p = atomicAdd(&cur[d >> 9], 1);
        staged[p] = (src[i] << 9) | (d & 511);   // src < 2^23, fits
    }
}

// ---------------- pass 2: per-bucket sort -> csr (CSR order) + rofs -----------
__global__ __launch_bounds__(256) void scat2_k(const int* __restrict__ bbase,
                                               const int* __restrict__ staged,
                                               int* __restrict__ csr,
                                               int* __restrict__ rofs,
                                               int n, int e, int nsb) {
    __shared__ int h[SBN];
    __shared__ int cur[SBN];
    __shared__ int wsum[8];
    int b = blockIdx.x;
    int tid = threadIdx.x;
    int lane = tid & 63, w = tid >> 6;
    int nlo = b << 9;
    int nn = n - nlo; if (nn > SBN) nn = SBN;   // live nodes in bucket
    int lo = bbase[b], hi = bbase[b + 1];
    h[tid] = 0;
    h[tid + 256] = 0;
    __syncthreads();
    for (int i = lo + tid; i < hi; i += 256) atomicAdd(&h[staged[i] & 511], 1);
    __syncthreads();
    int a0 = h[2 * tid], a1 = h[2 * tid + 1];
    int ps = a0 + a1;
    int inc = ps;
#pragma unroll
    for (int o = 1; o < 64; o <<= 1) {
        int t = __shfl_up(inc, o);
        if (lane >= o) inc += t;
    }
    if (lane == 63) wsum[w] = inc;
    __syncthreads();
    if (tid == 0) {
        int s = 0;
#pragma unroll
        for (int k = 0; k < 4; ++k) { int t = wsum[k]; wsum[k] = s; s += t; }
    }
    __syncthreads();
    int excl = inc - ps + wsum[w];
    cur[2 * tid] = excl;
    cur[2 * tid + 1] = excl + a0;
    __syncthreads();
    if (2 * tid < nn) rofs[nlo + 2 * tid] = lo + cur[2 * tid];
    if (2 * tid + 1 < nn) rofs[nlo + 2 * tid + 1] = lo + cur[2 * tid + 1];
    if (b == nsb - 1 && tid == 0) rofs[n] = e;
    __syncthreads();   // rofs must read cur before scatter mutates it
    for (int i = lo + tid; i < hi; i += 256) {
        int v = staged[i];
        int p = atomicAdd(&cur[v & 511], 1);
        csr[lo + p] = v >> 9;
    }
}

// ---------------- SAGE conv via MFMA, 16 nodes/block --------------------------
// Round-11 analysis: conv occupancy (42%) was GRID-limited (3125 blocks = 1.5x
// wave oversubscription), not resource-limited. 16 nodes/block -> 6250 blocks
// = 3x oversubscription; single-node gather keeps VGPR low. Wave w owns j-tile
// w, gathers 4 nodes, 1 M-tile of mfma_f32_16x16x32_bf16.
// POOL=true (conv2): epilogue reduces relu'd rows per graph segment (batch
// sorted) and atomicAdds into L2-resident sg[g*64+col].
template <int KIN, bool POOL>
__global__ __launch_bounds__(256) void conv_mfma(
    const int* __restrict__ rofs, const int* __restrict__ csr,
    const unsigned short* __restrict__ hin, const unsigned short* __restrict__ wpk,
    const float* __restrict__ bl, const int* __restrict__ batch,
    float* __restrict__ sg, unsigned short* __restrict__ hout, int n) {
    constexpr int KT = 2 * KIN;    // concat [agg|self]
    constexpr int ST = KT + 8;     // LDS row stride in ushorts (16B-aligned rows)
    constexpr int KS = KT / 32;    // MFMA k-steps
    constexpr int LPE = KIN / 8;   // lanes per edge row (16B each)
    constexpr int EPW = 64 / LPE;  // edges per wave-load
    __shared__ unsigned short __attribute__((aligned(16))) Ab[16 * ST];
    __shared__ float __attribute__((aligned(16))) Nb[4][16];
    __shared__ int ro[17];
    __shared__ int sb[16];

    int tid = threadIdx.x;
    int w = tid >> 6;              // wave id == j-tile
    int lane = tid & 63;
    int quad = lane >> 4;
    int l16 = lane & 15;
    int base = blockIdx.x * 16;
    int ncol = w * 16 + l16;

    if (tid < 17) ro[tid] = rofs[min(base + tid, n)];
    if (POOL && tid < 16) {
        int nd = base + tid;
        sb[tid] = (nd < n) ? batch[nd] : -1;
    }

    // B fragments: one 16B load each from packed weights
    frag_ab bfrag[KS];
#pragma unroll
    for (int s = 0; s < KS; ++s)
        bfrag[s] = *(const frag_ab*)&wpk[(((ncol * KS) + s) * 4 + quad) * 8];
    float bias = bl[ncol];
    __syncthreads();

    // ---- gather phase: wave w fills LDS rows w*4 .. w*4+3 ----
    int grp = lane / LPE;          // edge slot within a wave-load
    int p = lane % LPE;            // 16B chunk within a row
    for (int i = 0; i < 4; ++i) {
        int li = w * 4 + i;
        int node = base + li;
        if (node >= n) break;
        int beg = ro[li];
        int cnt = ro[li + 1] - beg;
        uint4 selfv = make_uint4(0u, 0u, 0u, 0u);
        if (grp == 1)
            selfv = *(const uint4*)&hin[(size_t)node * KIN + p * 8];
        float a[8] = {0.f, 0.f, 0.f, 0.f, 0.f, 0.f, 0.f, 0.f};
#pragma unroll 2
        for (int e = 0; e < cnt; e += EPW) {
            int ee = e + grp;
            bool ok = (ee < cnt);
            int s = csr[ok ? beg + ee : 0];
            uint4 u = *(const uint4*)&hin[(size_t)s * KIN + p * 8];
            if (ok) upadd(u, a);
        }
#pragma unroll
        for (int o = LPE; o < 64; o <<= 1) {
#pragma unroll
            for (int q = 0; q < 8; ++q) a[q] += __shfl_xor(a[q], o);
        }
        float inv = (cnt > 0) ? 1.0f / (float)cnt : 0.0f;
        if (grp == 0) {
            uint4 o4;
            o4.x = (unsigned)f2bf(a[0] * inv) | ((unsigned)f2bf(a[1] * inv) << 16);
            o4.y = (unsigned)f2bf(a[2] * inv) | ((unsigned)f2bf(a[3] * inv) << 16);
            o4.z = (unsigned)f2bf(a[4] * inv) | ((unsigned)f2bf(a[5] * inv) << 16);
            o4.w = (unsigned)f2bf(a[6] * inv) | ((unsigned)f2bf(a[7] * inv) << 16);
            *(uint4*)&Ab[li * ST + p * 8] = o4;
        } else if (grp == 1) {
            *(uint4*)&Ab[li * ST + KIN + p * 8] = selfv;
        }
    }
    __syncthreads();

    // ---- MFMA phase: wave w computes cols [w*16, w*16+16) for the M-tile ----
    frag_cd acc = (frag_cd){0.f, 0.f, 0.f, 0.f};
#pragma unroll
    for (int s = 0; s < KS; ++s) {
        frag_ab af = *(frag_ab*)&Ab[l16 * ST + s * 32 + quad * 8];
        acc = __builtin_amdgcn_mfma_f32_16x16x32_bf16(af, bfrag[s], acc, 0, 0, 0);
    }

    // ---- epilogue: bias, per-node L2 norm (cross-wave via LDS), relu ----
    float vv[4], q[4];
#pragma unroll
    for (int i = 0; i < 4; ++i) {
        float v = acc[i] + bias;   // D row = quad*4+i (node), col = l16
        vv[i] = v;
        q[i] = v * v;
    }
#pragma unroll
    for (int o = 1; o < 16; o <<= 1) {
#pragma unroll
        for (int i = 0; i < 4; ++i) q[i] += __shfl_xor(q[i], o);
    }
    if (l16 == 0)
        *(float4*)&Nb[w][quad * 4] = make_float4(q[0], q[1], q[2], q[3]);
    __syncthreads();

    float s0 = 0.f, s1 = 0.f, s2 = 0.f, s3 = 0.f;
#pragma unroll
    for (int ww = 0; ww < 4; ++ww) {
        float4 xq = *(const float4*)&Nb[ww][quad * 4];
        s0 += xq.x; s1 += xq.y; s2 += xq.z; s3 += xq.w;
    }
    float ss[4] = {s0, s1, s2, s3};
    float pv[4];
#pragma unroll
    for (int i = 0; i < 4; ++i) {
        float nv = fmaxf(sqrtf(ss[i]), EPSN);
        pv[i] = fmaxf(vv[i] / nv, 0.f);
    }

    if (!POOL) {
#pragma unroll
        for (int i = 0; i < 4; ++i) {
            int node = base + quad * 4 + i;
            if (node < n)
                hout[(size_t)node * 64 + ncol] = f2bf(pv[i]);
        }
    } else {
        // per-graph-segment sums; batch sorted -> g in [g0,g1], small span
        int g0 = sb[0];
        int g1 = sb[min(15, n - 1 - base)];
        for (int g = g0; g <= g1; ++g) {
            float s = 0.f;
#pragma unroll
            for (int i = 0; i < 4; ++i)
                if (sb[quad * 4 + i] == g) s += pv[i];
            s += __shfl_xor(s, 16);
            s += __shfl_xor(s, 32);
            if (quad == 0) atomicAdd(&sg[(size_t)g * 64 + ncol], s);
        }
    }
}

// ---------------- head MLP per graph (counts via binary search) ---------------
__global__ __launch_bounds__(64) void mlp_k(
    const float* __restrict__ sg, const int* __restrict__ batch, int n,
    const float* __restrict__ p1w, const float* __restrict__ p1b,
    const float* __restrict__ p2w, const float* __restrict__ p2b,
    const float* __restrict__ ow, const float* __restrict__ ob,
    float* __restrict__ out) {
    __shared__ float gmean[64];
    __shared__ float a1[64];
    __shared__ float a2[16];
    int g = blockIdx.x;
    int j = threadIdx.x;
    int lo = 0, hi = n;
    while (lo < hi) { int m = (lo + hi) >> 1; if (batch[m] < g) lo = m + 1; else hi = m; }
    int start = lo;
    hi = n;
    while (lo < hi) { int m = (lo + hi) >> 1; if (batch[m] < g + 1) lo = m + 1; else hi = m; }
    float c = (float)(lo - start);
    gmean[j] = sg[(size_t)g * 64 + j] / fmaxf(c, 1.0f);
    __syncthreads();
    float v = p1b[j];
#pragma unroll 8
    for (int k = 0; k < 64; ++k) v = fmaf(gmean[k], p1w[k * 64 + j], v);
    a1[j] = fmaxf(v, 0.f);
    __syncthreads();
    if (j < 16) {
        float v2 = p2b[j];
#pragma unroll 8
        for (int k = 0; k < 64; ++k) v2 = fmaf(a1[k], p2w[k * 16 + j], v2);
        a2[j] = fmaxf(v2, 0.f);
    }
    __syncthreads();
    if (j == 0) {
        float v3 = ob[0];
#pragma unroll
        for (int k = 0; k < 16; ++k) v3 = fmaf(a2[k], ow[k], v3);
        out[g] = v3;
    }
}

extern "C" void kernel_launch(void* const* d_in, const int* in_sizes, int n_in,
                              void* d_out, int out_size, void* d_ws, size_t ws_size,
                              hipStream_t stream) {
    const float* x     = (const float*)d_in[0];
    const int*   ei    = (const int*)d_in[1];
    const int*   batch = (const int*)d_in[2];
    const float* pre_w = (const float*)d_in[4];
    const float* pre_b = (const float*)d_in[5];
    const float* c1_wl = (const float*)d_in[6];
    const float* c1_bl = (const float*)d_in[7];
    const float* c1_wr = (const float*)d_in[8];
    const float* c2_wl = (const float*)d_in[9];
    const float* c2_bl = (const float*)d_in[10];
    const float* c2_wr = (const float*)d_in[11];
    const float* p1w   = (const float*)d_in[12];
    const float* p1b   = (const float*)d_in[13];
    const float* p2w   = (const float*)d_in[14];
    const float* p2b   = (const float*)d_in[15];
    const float* ow    = (const float*)d_in[16];
    const float* ob    = (const float*)d_in[17];

    const int N = in_sizes[0] / 5;
    const int E = in_sizes[1] / 2;
    const int G = out_size;
    const int NT = (E + TILE - 1) / TILE; // pass-1 tiles (196 <= 256)
    const int NSB = (N + SBN - 1) / SBN;  // coarse buckets (196 <= 256)
    const int* src = ei;
    const int* dst = ei + E;

    // workspace layout
    unsigned short* h0u = (unsigned short*)d_ws;                    // N*32 bf16
    unsigned short* h1u = h0u + (size_t)N * 32;                     // N*64 bf16
    unsigned short* wpk1 = h1u + (size_t)N * 64;                    // 64*64
    unsigned short* wpk2 = wpk1 + 64 * 64;                          // 64*128
    float* sg    = (float*)(wpk2 + 64 * 128);                       // G*64
    int* rofs    = (int*)(sg + (size_t)G * 64);                     // N+1
    int* bbase   = rofs + N + 1;                                    // NSB+1
    int* btot    = bbase + NSB + 1;                                 // NSB
    int* thistT  = btot + NSB;                                      // NSB*NT
    int* toffsT  = thistT + (size_t)NSB * NT;                       // NSB*NT
    int* staged  = toffsT + (size_t)NSB * NT;                       // E
    int* csr     = staged + E;                                      // E

    pre_linear<<<(N * 32 + 255) / 256, 256, 0, stream>>>(x, pre_w, pre_b, h0u, N);
    prep_k<<<(64 * 64 + 64 * 128 + G * 64 + 255) / 256, 256, 0, stream>>>(
        c1_wl, c1_wr, wpk1, c2_wl, c2_wr, wpk2, sg, G * 64);

    // two-level bucket sort -> csr in CSR order + rofs
    thist_k<<<NT, 256, 0, stream>>>(dst, thistT, E, NSB, NT);
    tscan_k<<<NSB, 256, 0, stream>>>(thistT, toffsT, btot, NT);
    bscan_k<<<1, 256, 0, stream>>>(btot, bbase, NSB, E);
    scat1_k<<<NT, 256, 0, stream>>>(src, dst, toffsT, bbase, staged, E, NSB, NT);
    scat2_k<<<NSB, 256, 0, stream>>>(bbase, staged, csr, rofs, N, E, NSB);

    conv_mfma<32, false><<<(N + 15) / 16, 256, 0, stream>>>(
        rofs, csr, h0u, wpk1, c1_bl, batch, sg, h1u, N);
    conv_mfma<64, true><<<(N + 15) / 16, 256, 0, stream>>>(
        rofs, csr, h1u, wpk2, c2_bl, batch, sg, nullptr, N);

    mlp_k<<<G, 64, 0, stream>>>(sg, batch, N, p1w, p1b, p2w, p2b, ow, ob,
                                (float*)d_out);
}